// Round 12
// baseline (1714.410 us; speedup 1.0000x reference)
//
#include <hip/hip_runtime.h>
#include <math.h>

constexpr int B_ = 64, S_ = 256, D_ = 512, H_ = 256, NC_ = 3;
constexpr int BS = B_ * S_;     // 16384
constexpr int G4 = 4 * H_;      // 1024

typedef __attribute__((ext_vector_type(4))) float f32x4;
typedef __attribute__((ext_vector_type(8))) short s16x8;
typedef unsigned short u16;
typedef unsigned long long u64;

template<int ACT>
static __device__ __forceinline__ float activate(float v) {
  if constexpr (ACT == 1) return v > 0.f ? v : 0.f;
  else if constexpr (ACT == 2) return 1.f / (1.f + expf(-v));
  else return v;
}

static __device__ __forceinline__ u16 f2bf_rne(float f) {
  unsigned u = __float_as_uint(f);
  return (u16)((u + 0x7FFFu + ((u >> 16) & 1u)) >> 16);
}
static __device__ __forceinline__ float bf2f(u16 h) {
  return __uint_as_float(((unsigned)h) << 16);
}
static __device__ __forceinline__ void splitf(float f, u16& h, u16& l) {
  h = f2bf_rne(f);
  float r = f - bf2f(h);
  l = f2bf_rne(r);
}

// ---------------- split precompute kernels ----------------
__global__ __launch_bounds__(256) void split_w(
    const float* __restrict__ src, u16* __restrict__ h, u16* __restrict__ l, int n4)
{
  int i = blockIdx.x * 256 + threadIdx.x;
  if (i >= n4) return;
  float4 v = ((const float4*)src)[i];
  ushort4 hh, ll;
  splitf(v.x, hh.x, ll.x); splitf(v.y, hh.y, ll.y);
  splitf(v.z, hh.z, ll.z); splitf(v.w, hh.w, ll.w);
  ((ushort4*)h)[i] = hh;
  ((ushort4*)l)[i] = ll;
}

// Xemb[m][k] = embed[gidx[m]][k]  (split)
__global__ __launch_bounds__(256) void gather_split(
    const float* __restrict__ embed, const int* __restrict__ gidx,
    u16* __restrict__ h, u16* __restrict__ l)
{
  int i = blockIdx.x * 256 + threadIdx.x;   // over BS*D/4
  if (i >= BS * D_ / 4) return;
  int r = i >> 7;            // row (D/4 = 128 float4 per row)
  int c = (i & 127) << 2;
  float4 v = *(const float4*)(embed + (size_t)gidx[r] * D_ + c);
  ushort4 hh, ll;
  splitf(v.x, hh.x, ll.x); splitf(v.y, hh.y, ll.y);
  splitf(v.z, hh.z, ll.z); splitf(v.w, hh.w, ll.w);
  ((ushort4*)h)[i] = hh;
  ((ushort4*)l)[i] = ll;
}

// ---------------- split-bf16 MFMA GEMM, 128x128 tile ----------------
template<int ACT, bool BT, bool ADDC, bool ASPL, bool BSPL, bool OSPL>
__global__ __launch_bounds__(256) void mgemm(
    const float* __restrict__ Af, const u16* __restrict__ Ah, const u16* __restrict__ Al,
    const float* __restrict__ Bf, const u16* __restrict__ Bh, const u16* __restrict__ Bl,
    const float* __restrict__ bias, const float* __restrict__ Cin,
    float* __restrict__ Co, u16* __restrict__ Oh, u16* __restrict__ Ol,
    int M, int N, int K, int ldb, long sA, long sB, long sC)
{
  __shared__ u16 AH[128][40];
  __shared__ u16 AL[128][40];
  __shared__ u16 BH[128][40];
  __shared__ u16 BL[128][40];

  const int tid = threadIdx.x;
  const int w = tid >> 6, l = tid & 63;
  const int m0 = blockIdx.x * 128, n0 = blockIdx.y * 128;
  const long zA = (long)blockIdx.z * sA;
  const long zB = (long)blockIdx.z * sB;
  const long zC = (long)blockIdx.z * sC;

  f32x4 acc[2][8];
  #pragma unroll
  for (int i = 0; i < 2; ++i)
    #pragma unroll
    for (int j = 0; j < 8; ++j) acc[i][j] = (f32x4){0.f, 0.f, 0.f, 0.f};

  const int ar = tid >> 1, ahh = tid & 1;
  const int bk = tid >> 3, bnq = tid & 7;
  const int lr = l & 15, lk = (l >> 4) * 8;

  for (int kt = 0; kt < K; kt += 32) {
    {
      int m = m0 + ar;
      if constexpr (ASPL) {
        s16x8 h0 = (s16x8)0, h1 = (s16x8)0, l0 = (s16x8)0, l1 = (s16x8)0;
        if (m < M) {
          const u16* ph = Ah + zA + (size_t)m * K + kt + ahh * 16;
          const u16* pl = Al + zA + (size_t)m * K + kt + ahh * 16;
          h0 = *(const s16x8*)ph; h1 = *(const s16x8*)(ph + 8);
          l0 = *(const s16x8*)pl; l1 = *(const s16x8*)(pl + 8);
        }
        *(s16x8*)&AH[ar][ahh * 16] = h0; *(s16x8*)&AH[ar][ahh * 16 + 8] = h1;
        *(s16x8*)&AL[ar][ahh * 16] = l0; *(s16x8*)&AL[ar][ahh * 16 + 8] = l1;
      } else {
        float vv[16];
        if (m < M) {
          const float* pf = Af + zA + (size_t)m * K + kt + ahh * 16;
          #pragma unroll
          for (int c = 0; c < 4; ++c) {
            float4 v = ((const float4*)pf)[c];
            vv[c * 4] = v.x; vv[c * 4 + 1] = v.y; vv[c * 4 + 2] = v.z; vv[c * 4 + 3] = v.w;
          }
        } else {
          #pragma unroll
          for (int c = 0; c < 16; ++c) vv[c] = 0.f;
        }
        u16 hh[16], ll[16];
        #pragma unroll
        for (int c = 0; c < 16; ++c) splitf(vv[c], hh[c], ll[c]);
        *(s16x8*)&AH[ar][ahh * 16] = *(s16x8*)&hh[0];
        *(s16x8*)&AH[ar][ahh * 16 + 8] = *(s16x8*)&hh[8];
        *(s16x8*)&AL[ar][ahh * 16] = *(s16x8*)&ll[0];
        *(s16x8*)&AL[ar][ahh * 16 + 8] = *(s16x8*)&ll[8];
      }
    }
    if constexpr (BT) {
      if constexpr (BSPL) {
        const u16* ph = Bh + zB + (size_t)(n0 + ar) * ldb + kt + ahh * 16;
        const u16* pl = Bl + zB + (size_t)(n0 + ar) * ldb + kt + ahh * 16;
        *(s16x8*)&BH[ar][ahh * 16] = *(const s16x8*)ph;
        *(s16x8*)&BH[ar][ahh * 16 + 8] = *(const s16x8*)(ph + 8);
        *(s16x8*)&BL[ar][ahh * 16] = *(const s16x8*)pl;
        *(s16x8*)&BL[ar][ahh * 16 + 8] = *(const s16x8*)(pl + 8);
      } else {
        const float* pf = Bf + zB + (size_t)(n0 + ar) * ldb + kt + ahh * 16;
        float vv[16];
        #pragma unroll
        for (int c = 0; c < 4; ++c) {
          float4 v = ((const float4*)pf)[c];
          vv[c * 4] = v.x; vv[c * 4 + 1] = v.y; vv[c * 4 + 2] = v.z; vv[c * 4 + 3] = v.w;
        }
        u16 hh[16], ll[16];
        #pragma unroll
        for (int c = 0; c < 16; ++c) splitf(vv[c], hh[c], ll[c]);
        *(s16x8*)&BH[ar][ahh * 16] = *(s16x8*)&hh[0];
        *(s16x8*)&BH[ar][ahh * 16 + 8] = *(s16x8*)&hh[8];
        *(s16x8*)&BL[ar][ahh * 16] = *(s16x8*)&ll[0];
        *(s16x8*)&BL[ar][ahh * 16 + 8] = *(s16x8*)&ll[8];
      }
    } else {
      const u16* ph = Bh + zB + (size_t)(kt + bk) * ldb + n0 + bnq * 16;
      const u16* pl = Bl + zB + (size_t)(kt + bk) * ldb + n0 + bnq * 16;
      s16x8 h8a = *(const s16x8*)ph, h8b = *(const s16x8*)(ph + 8);
      s16x8 l8a = *(const s16x8*)pl, l8b = *(const s16x8*)(pl + 8);
      #pragma unroll
      for (int jj = 0; jj < 8; ++jj) {
        BH[bnq * 16 + jj][bk] = (u16)h8a[jj];
        BH[bnq * 16 + 8 + jj][bk] = (u16)h8b[jj];
        BL[bnq * 16 + jj][bk] = (u16)l8a[jj];
        BL[bnq * 16 + 8 + jj][bk] = (u16)l8b[jj];
      }
    }
    __syncthreads();

    s16x8 afh[2], afl[2];
    #pragma unroll
    for (int i = 0; i < 2; ++i) {
      afh[i] = *(const s16x8*)&AH[w * 32 + i * 16 + lr][lk];
      afl[i] = *(const s16x8*)&AL[w * 32 + i * 16 + lr][lk];
    }
    #pragma unroll
    for (int j = 0; j < 8; ++j) {
      s16x8 bfh = *(const s16x8*)&BH[j * 16 + lr][lk];
      s16x8 bfl = *(const s16x8*)&BL[j * 16 + lr][lk];
      #pragma unroll
      for (int i = 0; i < 2; ++i) {
        acc[i][j] = __builtin_amdgcn_mfma_f32_16x16x32_bf16(afl[i], bfh, acc[i][j], 0, 0, 0);
        acc[i][j] = __builtin_amdgcn_mfma_f32_16x16x32_bf16(afh[i], bfl, acc[i][j], 0, 0, 0);
        acc[i][j] = __builtin_amdgcn_mfma_f32_16x16x32_bf16(afh[i], bfh, acc[i][j], 0, 0, 0);
      }
    }
    __syncthreads();
  }

  const int rl = (l >> 4) * 4;
  #pragma unroll
  for (int j = 0; j < 8; ++j) {
    int n = n0 + j * 16 + lr;
    float bv = bias ? bias[n] : 0.f;
    #pragma unroll
    for (int i = 0; i < 2; ++i) {
      #pragma unroll
      for (int e = 0; e < 4; ++e) {
        int m = m0 + w * 32 + i * 16 + rl + e;
        if (m < M) {
          float v = acc[i][j][e] + bv;
          if constexpr (ADDC) v += Cin[zC + (size_t)m * N + n];
          v = activate<ACT>(v);
          if constexpr (OSPL) {
            u16 hh, ll; splitf(v, hh, ll);
            Oh[zC + (size_t)m * N + n] = hh;
            Ol[zC + (size_t)m * N + n] = ll;
          } else {
            Co[zC + (size_t)m * N + n] = v;
          }
        }
      }
    }
  }
}

// ---------------- distributed LSTM ----------------
// WF layout: q = (((dir*8+j)*4+w)*8+kt)*2+nt : hi at q*1024 + lane*8, lo at +512
__global__ __launch_bounds__(256) void wf_prep(
    const float* __restrict__ Wf, const float* __restrict__ Wb, u16* __restrict__ WF)
{
  int gid = blockIdx.x * 256 + threadIdx.x;   // 65536
  int lane = gid & 63;
  int nt = (gid >> 6) & 1;
  int kt = (gid >> 7) & 7;
  int w  = (gid >> 10) & 3;
  int j  = (gid >> 12) & 7;
  int dir = gid >> 15;
  const float* W = dir ? Wb : Wf;
  int r = w * 256 + j * 32 + nt * 16 + (lane & 15);
  int kb = kt * 32 + (lane >> 4) * 8;
  const float* src = W + (size_t)r * H_ + kb;
  u16 hh[8], ll[8];
  #pragma unroll
  for (int c = 0; c < 2; ++c) {
    float4 v = ((const float4*)src)[c];
    splitf(v.x, hh[c*4+0], ll[c*4+0]); splitf(v.y, hh[c*4+1], ll[c*4+1]);
    splitf(v.z, hh[c*4+2], ll[c*4+2]); splitf(v.w, hh[c*4+3], ll[c*4+3]);
  }
  size_t off = (size_t)(gid >> 6) * 1024 + (size_t)lane * 8;
  *(s16x8*)(WF + off)       = *(s16x8*)&hh[0];
  *(s16x8*)(WF + off + 512) = *(s16x8*)&ll[0];
}

// re-tag BOTH ring buffers (contiguous 128K u64) to generation 3 in both halves
__global__ __launch_bounds__(256) void ring_init(u64* __restrict__ ring64)
{
  int i = blockIdx.x * 256 + threadIdx.x;   // 131072
  __hip_atomic_store(&ring64[i], 0x0000000300000003ULL,
                     __ATOMIC_RELAXED, __HIP_MEMORY_SCOPE_AGENT);
}

// grid 64: grp = bid&7 (dir*4+bg), j = bid>>3. 256 threads (4 waves).
// Dual-path tagged ring: word = {fp32 h1 | fp32 h0}, gen tag in the 2 LSBs of
// BOTH halves (tear-detect). Producer stores the word to ringF (plain store ->
// local L2, fast same-XCD path) AND ring64 (agent atomic -> IF$, fallback).
// Consumer: 4 fast tries via sc0 (L1-bypass, L2-hit) loads, then IF$ poll.
// Stale fast words either fail the tag check or (prev-replay lines) carry the
// bit-identical value for the same t (determinism) -- always correct.
__global__ __launch_bounds__(256, 1) void lstm_dist(
    const float* __restrict__ GX, const u16* __restrict__ WF,
    const int* __restrict__ lens, u16* __restrict__ outH, u16* __restrict__ outL,
    u64* __restrict__ ring64, u64* __restrict__ ringF)
{
  const int bid = blockIdx.x;
  const int grp = bid & 7;
  const int j   = bid >> 3;
  const int dir = grp >> 2;
  const int bg  = grp & 3;
  const int b0g = bg * 16;
  const int tid = threadIdx.x;
  const int w = tid >> 6, l = tid & 63;

  const float* gx = GX + (size_t)dir * ((size_t)BS * G4);

  __shared__ int slen[16];
  __shared__ __align__(16) u16 AHs[16][264];
  __shared__ __align__(16) u16 ALs[16][264];
  __shared__ float act[2][4][16][33];    // double-buffered by t&1
  if (tid < 16) slen[tid] = lens[b0g + tid];
  __syncthreads();

  s16x8 wh[8][2], wl[8][2];
  #pragma unroll
  for (int kt = 0; kt < 8; ++kt)
    #pragma unroll
    for (int nt = 0; nt < 2; ++nt) {
      size_t q = ((size_t)(((dir * 8 + j) * 4 + w) * 8 + kt) * 2 + nt);
      const u16* p = WF + q * 1024 + (size_t)l * 8;
      wh[kt][nt] = *(const s16x8*)p;
      wl[kt][nt] = *(const s16x8*)(p + 512);
    }

  const int ub = tid >> 4;
  const int uu = (tid & 15) * 2;
  const int len_b = slen[ub];
  float c0s = 0.f, c1s = 0.f, h0s = 0.f, h1s = 0.f;

  const int lr = l & 15, lkb = (l >> 4) * 8;

  for (int t = 0; t < S_; ++t) {
    float gxv[2][4];
    #pragma unroll
    for (int nt = 0; nt < 2; ++nt)
      #pragma unroll
      for (int e = 0; e < 4; ++e) {
        int b = (l >> 4) * 4 + e;
        int len = slen[b];
        int pos = dir ? (t < len ? len - 1 - t : t) : t;
        gxv[nt][e] = gx[(size_t)((b0g + b) * S_ + pos) * G4 + (w * 256 + j * 32 + nt * 16 + lr)];
      }

    f32x4 acc[2];
    acc[0] = (f32x4){0.f, 0.f, 0.f, 0.f};
    acc[1] = (f32x4){0.f, 0.f, 0.f, 0.f};

    if (t > 0) {
      const unsigned gen = (unsigned)(((t - 1) >> 2) & 3);
      const int slot = (t - 1) & 3;
      const size_t rbase = ((size_t)slot * 8 + grp) * (16 * 128);
      u64* rb = ring64 + rbase;
      const u64* rf = ringF + rbase;
      u64 v[8];
      const u64* q0 = rf + 0 * 256 + tid;
      const u64* q1 = rf + 1 * 256 + tid;
      const u64* q2 = rf + 2 * 256 + tid;
      const u64* q3 = rf + 3 * 256 + tid;
      const u64* q4 = rf + 4 * 256 + tid;
      const u64* q5 = rf + 5 * 256 + tid;
      const u64* q6 = rf + 6 * 256 + tid;
      const u64* q7 = rf + 7 * 256 + tid;
      bool got = false;
      for (int tryi = 0; tryi < 4 && !got; ++tryi) {
        asm volatile(
          "global_load_dwordx2 %0, %8, off sc0\n\t"
          "global_load_dwordx2 %1, %9, off sc0\n\t"
          "global_load_dwordx2 %2, %10, off sc0\n\t"
          "global_load_dwordx2 %3, %11, off sc0\n\t"
          "global_load_dwordx2 %4, %12, off sc0\n\t"
          "global_load_dwordx2 %5, %13, off sc0\n\t"
          "global_load_dwordx2 %6, %14, off sc0\n\t"
          "global_load_dwordx2 %7, %15, off sc0\n\t"
          "s_waitcnt vmcnt(0)"
          : "=&v"(v[0]), "=&v"(v[1]), "=&v"(v[2]), "=&v"(v[3]),
            "=&v"(v[4]), "=&v"(v[5]), "=&v"(v[6]), "=&v"(v[7])
          : "v"(q0), "v"(q1), "v"(q2), "v"(q3),
            "v"(q4), "v"(q5), "v"(q6), "v"(q7)
          : "memory");
        unsigned bad = 0;
        #pragma unroll
        for (int k = 0; k < 8; ++k) {
          bad |= ((unsigned)v[k] & 3u) ^ gen;
          bad |= ((unsigned)(v[k] >> 32) & 3u) ^ gen;
        }
        got = (bad == 0);
      }
      if (!got) {
        unsigned need = 0xFFu;
        do {
          unsigned nn = 0;
          #pragma unroll
          for (int k = 0; k < 8; ++k)
            if ((need >> k) & 1)
              v[k] = __hip_atomic_load(&rb[k * 256 + tid], __ATOMIC_RELAXED, __HIP_MEMORY_SCOPE_AGENT);
          #pragma unroll
          for (int k = 0; k < 8; ++k)
            if (((need >> k) & 1) &&
                ((((unsigned)v[k] & 3u) != gen) || (((unsigned)(v[k] >> 32) & 3u) != gen)))
              nn |= 1u << k;
          need = nn;
        } while (need);
      }
      #pragma unroll
      for (int k = 0; k < 8; ++k) {
        int idx = k * 256 + tid;
        int b = idx >> 7, p = idx & 127;
        float f0 = __uint_as_float((unsigned)v[k] & ~3u);
        float f1 = __uint_as_float((unsigned)(v[k] >> 32) & ~3u);
        u16 hh0, ll0, hh1, ll1;
        splitf(f0, hh0, ll0); splitf(f1, hh1, ll1);
        *(unsigned*)&AHs[b][2 * p] = (unsigned)hh0 | ((unsigned)hh1 << 16);
        *(unsigned*)&ALs[b][2 * p] = (unsigned)ll0 | ((unsigned)ll1 << 16);
      }
      __syncthreads();
      #pragma unroll
      for (int kt = 0; kt < 8; ++kt) {
        s16x8 ah = *(const s16x8*)&AHs[lr][kt * 32 + lkb];
        s16x8 al = *(const s16x8*)&ALs[lr][kt * 32 + lkb];
        #pragma unroll
        for (int nt = 0; nt < 2; ++nt) {
          acc[nt] = __builtin_amdgcn_mfma_f32_16x16x32_bf16(al, wh[kt][nt], acc[nt], 0, 0, 0);
          acc[nt] = __builtin_amdgcn_mfma_f32_16x16x32_bf16(ah, wl[kt][nt], acc[nt], 0, 0, 0);
          acc[nt] = __builtin_amdgcn_mfma_f32_16x16x32_bf16(ah, wh[kt][nt], acc[nt], 0, 0, 0);
        }
      }
    }

    const int pb = t & 1;
    #pragma unroll
    for (int nt = 0; nt < 2; ++nt)
      #pragma unroll
      for (int e = 0; e < 4; ++e) {
        float v = acc[nt][e] + gxv[nt][e];
        v = (w == 2) ? tanhf(v) : 1.f / (1.f + expf(-v));
        act[pb][w][(l >> 4) * 4 + e][nt * 16 + lr] = v;
      }
    __syncthreads();

    {
      int pos = dir ? (t < len_b ? len_b - 1 - t : t) : t;
      bool valid = t < len_b;
      float i0 = act[pb][0][ub][uu],     f0 = act[pb][1][ub][uu],     g0 = act[pb][2][ub][uu],     o0 = act[pb][3][ub][uu];
      float i1 = act[pb][0][ub][uu + 1], f1 = act[pb][1][ub][uu + 1], g1 = act[pb][2][ub][uu + 1], o1 = act[pb][3][ub][uu + 1];
      float cn0 = fmaf(f0, c0s, i0 * g0), cn1 = fmaf(f1, c1s, i1 * g1);
      float hn0 = o0 * tanhf(cn0), hn1 = o1 * tanhf(cn1);
      if (valid) { c0s = cn0; h0s = hn0; c1s = cn1; h1s = hn1; }
      unsigned gen = (unsigned)((t >> 2) & 3);
      unsigned a0 = (__float_as_uint(h0s) & ~3u) | gen;
      unsigned a1 = (__float_as_uint(h1s) & ~3u) | gen;
      u64 word = ((u64)a1 << 32) | (u64)a0;
      const int slot = t & 3;
      size_t ridx = ((size_t)slot * 8 + grp) * (16 * 128) + (size_t)ub * 128 + j * 16 + (tid & 15);
      *(volatile u64*)&ringF[ridx] = word;                     // L2 fast path
      __hip_atomic_store(&ring64[ridx], word, __ATOMIC_RELAXED, __HIP_MEMORY_SCOPE_AGENT);
      float ov0 = valid ? hn0 : 0.f, ov1 = valid ? hn1 : 0.f;
      u16 oh0, qq0, oh1, qq1;
      splitf(ov0, oh0, qq0); splitf(ov1, oh1, qq1);
      size_t obase = (size_t)((b0g + ub) * S_ + pos) * (2 * H_) + dir * H_ + j * 32 + uu;
      *(ushort2*)&outH[obase] = make_ushort2(oh0, oh1);
      *(ushort2*)&outL[obase] = make_ushort2(qq0, qq1);
    }
    // no trailing barrier: act double-buffered; AHs writes gated by next
    // iteration's post-staging barrier.
  }
}

// span-based aspect mean: only the <=5 rows with amask==0 contribute
__global__ __launch_bounds__(512) void asps_k(
    const u16* __restrict__ lh, const u16* __restrict__ ll,
    const float* __restrict__ amask, const int* __restrict__ alen, float* __restrict__ asps)
{
  int b = blockIdx.x, tid = threadIdx.x;
  __shared__ int sstart;
  if (tid == 0) sstart = S_;
  __syncthreads();
  if (tid < S_ && amask[b * S_ + tid] == 0.f) atomicMin(&sstart, tid);
  __syncthreads();
  const int start = sstart;
  const int len = alen[b];
  float acc = 0.f;
  for (int k = 0; k < len; ++k) {
    size_t i = ((size_t)(b * S_ + start + k)) * D_ + tid;
    acc += bf2f(lh[i]) + bf2f(ll[i]);
  }
  asps[b * D_ + tid] = acc / (float)len;
}

__global__ __launch_bounds__(256) void softmax_rows(
    const float* __restrict__ p_, const float* __restrict__ mask,
    u16* __restrict__ ph, u16* __restrict__ pl)
{
  const int row = blockIdx.x;
  const int b = row >> 8;
  const int tid = threadIdx.x;
  const float* p = p_ + (size_t)row * S_;
  float v = p[tid] + mask[(b << 8) | tid];
  float m = v;
  #pragma unroll
  for (int off = 32; off > 0; off >>= 1) m = fmaxf(m, __shfl_xor(m, off));
  __shared__ float r1[4];
  __shared__ float r2[4];
  const int w = tid >> 6, l = tid & 63;
  if (l == 0) r1[w] = m;
  __syncthreads();
  m = fmaxf(fmaxf(r1[0], r1[1]), fmaxf(r1[2], r1[3]));
  float e = expf(v - m);
  float s = e;
  #pragma unroll
  for (int off = 32; off > 0; off >>= 1) s += __shfl_xor(s, off);
  if (l == 0) r2[w] = s;
  __syncthreads();
  s = r2[0] + r2[1] + r2[2] + r2[3];
  float o = e / s;
  u16 hh, ll; splitf(o, hh, ll);
  ph[(size_t)row * S_ + tid] = hh;
  pl[(size_t)row * S_ + tid] = ll;
}

__global__ __launch_bounds__(256) void xupdate(
    const u16* __restrict__ xh, const u16* __restrict__ xl,
    const float4* __restrict__ sc, const float4* __restrict__ lin,
    u16* __restrict__ oh, u16* __restrict__ ol, int n4)
{
  int i = blockIdx.x * 256 + threadIdx.x;
  if (i >= n4) return;
  ushort4 h4 = ((const ushort4*)xh)[i];
  ushort4 l4 = ((const ushort4*)xl)[i];
  float4 s = sc[i], lv = lin[i];
  float x0 = bf2f(h4.x) + bf2f(l4.x);
  float x1 = bf2f(h4.y) + bf2f(l4.y);
  float x2 = bf2f(h4.z) + bf2f(l4.z);
  float x3 = bf2f(h4.w) + bf2f(l4.w);
  float o0 = s.x * lv.x + (1.f - s.x) * x0;
  float o1 = s.y * lv.y + (1.f - s.y) * x1;
  float o2 = s.z * lv.z + (1.f - s.z) * x2;
  float o3 = s.w * lv.w + (1.f - s.w) * x3;
  ushort4 hh, ll;
  splitf(o0, hh.x, ll.x); splitf(o1, hh.y, ll.y);
  splitf(o2, hh.z, ll.z); splitf(o3, hh.w, ll.w);
  ((ushort4*)oh)[i] = hh;
  ((ushort4*)ol)[i] = ll;
}

__global__ __launch_bounds__(256) void final_sc_k(
    const float* __restrict__ Qp, const float* __restrict__ Kp,
    const float* __restrict__ smask, float* __restrict__ outsc)
{
  int b = blockIdx.x, tid = threadIdx.x;
  __shared__ float q[D_];
  q[tid] = Qp[b * D_ + tid];
  q[tid + 256] = Qp[b * D_ + tid + 256];
  __syncthreads();
  const float4* kr = (const float4*)(Kp + ((size_t)(b * S_ + tid)) * D_);
  float acc = 0.f;
  #pragma unroll 4
  for (int d = 0; d < D_ / 4; ++d) {
    float4 kv = kr[d];
    acc += q[4 * d] * kv.x + q[4 * d + 1] * kv.y + q[4 * d + 2] * kv.z + q[4 * d + 3] * kv.w;
  }
  float v = acc / sqrtf((float)D_) + smask[b * S_ + tid];
  float m = v;
  #pragma unroll
  for (int off = 32; off > 0; off >>= 1) m = fmaxf(m, __shfl_xor(m, off));
  __shared__ float r1[4];
  __shared__ float r2[4];
  const int w = tid >> 6, l = tid & 63;
  if (l == 0) r1[w] = m;
  __syncthreads();
  m = fmaxf(fmaxf(r1[0], r1[1]), fmaxf(r1[2], r1[3]));
  float e = expf(v - m);
  float s = e;
  #pragma unroll
  for (int off = 32; off > 0; off >>= 1) s += __shfl_xor(s, off);
  if (l == 0) r2[w] = s;
  __syncthreads();
  s = r2[0] + r2[1] + r2[2] + r2[3];
  outsc[b * S_ + tid] = e / s;
}

__global__ __launch_bounds__(512) void zero_outv(float* __restrict__ p)
{
  p[blockIdx.x * 512 + threadIdx.x] = 0.f;
}

// k-split weighted sum: grid (B, 8), each block sums a 32-k slice, atomicAdd.
__global__ __launch_bounds__(512) void out_vec_k(
    const float* __restrict__ sc, const float* __restrict__ Vp, float* __restrict__ outv)
{
  int b = blockIdx.x, d = threadIdx.x;
  int k0 = blockIdx.y * 32;
  __shared__ float s[32];
  if (d < 32) s[d] = sc[b * S_ + k0 + d];
  __syncthreads();
  float acc = 0.f;
  #pragma unroll
  for (int k = 0; k < 32; ++k)
    acc = fmaf(s[k], Vp[((size_t)(b * S_ + k0 + k)) * D_ + d], acc);
  atomicAdd(&outv[b * D_ + d], acc);
}

__global__ __launch_bounds__(192) void logits_k(
    const float* __restrict__ outv, const float* __restrict__ Wd,
    const float* __restrict__ bd, float* __restrict__ out)
{
  int b = blockIdx.x;
  int c = threadIdx.x >> 6, l = threadIdx.x & 63;
  float acc = 0.f;
  for (int d = l; d < D_; d += 64) acc = fmaf(outv[b * D_ + d], Wd[c * D_ + d], acc);
  #pragma unroll
  for (int off = 32; off > 0; off >>= 1) acc += __shfl_down(acc, off);
  if (l == 0) out[b * NC_ + c] = acc + bd[c];
}

extern "C" void kernel_launch(void* const* d_in, const int* in_sizes, int n_in,
                              void* d_out, int out_size, void* d_ws, size_t ws_size,
                              hipStream_t stream)
{
  const int*   seqs_id   = (const int*)d_in[0];
  const int*   seqs_len  = (const int*)d_in[1];
  const int*   asps_len  = (const int*)d_in[2];
  const float* asps_mask = (const float*)d_in[3];
  const float* sent_mask = (const float*)d_in[4];
  const float* embed     = (const float*)d_in[5];
  const float* Wih_f     = (const float*)d_in[6];
  const float* Whh_f     = (const float*)d_in[7];
  const float* b_f       = (const float*)d_in[8];
  const float* Wih_b     = (const float*)d_in[9];
  const float* Whh_b     = (const float*)d_in[10];
  const float* b_b       = (const float*)d_in[11];
  const float* W_cpt     = (const float*)d_in[12];
  const float* b_cpt     = (const float*)d_in[13];
  const float* W_as      = (const float*)d_in[14];
  const float* b_as      = (const float*)d_in[15];
  const float* Wq        = (const float*)d_in[16];
  const float* bq        = (const float*)d_in[17];
  const float* Wk        = (const float*)d_in[18];
  const float* bk        = (const float*)d_in[19];
  const float* Wv        = (const float*)d_in[20];
  const float* bv        = (const float*)d_in[21];
  const float* Wd        = (const float*)d_in[22];
  const float* bd        = (const float*)d_in[23];

  float* w = (float*)d_ws;
  size_t off = 0;
  auto alloc = [&](size_t words) { size_t o = off; off += words; return o; };
  struct Split { u16* h; u16* l; };
  auto salloc = [&](size_t n) {
    size_t o = alloc(n);
    Split s; s.h = (u16*)(w + o); s.l = (u16*)(w + o) + n; return s;
  };

  // ---- persistent ----
  const size_t off_wf    = alloc(524288);           // WF: 2 MB (1M u16)
  const size_t off_ring  = alloc(131072);           // ring64: 64K u64 = 512 KB (IF$)
  const size_t off_ringf = alloc(131072);           // ringF:  64K u64 = 512 KB (L2)
  Split sWihF = salloc(4ul * H_ * D_);
  Split sWihB = salloc(4ul * H_ * D_);
  Split sWcpt = salloc((size_t)D_ * 2 * D_);
  Split sWas  = salloc((size_t)D_ * D_);
  Split sWk   = salloc((size_t)D_ * D_);
  Split sWv   = salloc((size_t)D_ * D_);
  Split sWq   = salloc((size_t)D_ * D_);
  Split sLstm = salloc((size_t)BS * D_);
  const size_t off_asps = alloc((size_t)B_ * D_);
  const size_t off_qp   = alloc((size_t)B_ * D_);
  const size_t off_outv = alloc((size_t)B_ * D_);

  // ---- dynamic region ----
  const size_t dyn0 = off;
  Split sXemb; sXemb.h = (u16*)(w + dyn0); sXemb.l = sXemb.h + (size_t)BS * D_;
  float* GX = w + dyn0 + (size_t)BS * D_;
  size_t p2 = dyn0;
  float* scoreF = w + p2;                 p2 += (size_t)B_ * S_ * S_;
  Split sScore; sScore.h = (u16*)(w + p2); sScore.l = sScore.h + (size_t)B_ * S_ * S_; p2 += (size_t)B_ * S_ * S_;
  Split sAttn;  sAttn.h  = (u16*)(w + p2); sAttn.l  = sAttn.h + (size_t)BS * D_;       p2 += (size_t)BS * D_;
  float* lin = w + p2;                    p2 += (size_t)BS * D_;
  float* scl = w + p2;                    p2 += (size_t)BS * D_;
  Split sX;     sX.h     = (u16*)(w + p2); sX.l     = sX.h + (size_t)BS * D_;           p2 += (size_t)BS * D_;

  u16* WF      = (u16*)(w + off_wf);
  u64* ring64  = (u64*)(w + off_ring);
  u64* ringF   = (u64*)(w + off_ringf);
  float* aspsb = w + off_asps;
  float* qp    = w + off_qp;
  float* outv  = w + off_outv;
  float* Kp    = (float*)sAttn.h;
  float* Vp    = lin;
  float* logits = (float*)d_out;
  float* outsc  = (float*)d_out + B_ * NC_;

  // ---- prep ----
  ring_init<<<512, 256, 0, stream>>>(ring64);   // covers ring64 + ringF (contiguous)
  wf_prep<<<256, 256, 0, stream>>>(Whh_f, Whh_b, WF);
  split_w<<<512, 256, 0, stream>>>(Wih_f, sWihF.h, sWihF.l, H_ * D_);
  split_w<<<512, 256, 0, stream>>>(Wih_b, sWihB.h, sWihB.l, H_ * D_);
  split_w<<<512, 256, 0, stream>>>(W_cpt, sWcpt.h, sWcpt.l, D_ * 2 * D_ / 4);
  split_w<<<256, 256, 0, stream>>>(W_as, sWas.h, sWas.l, D_ * D_ / 4);
  split_w<<<256, 256, 0, stream>>>(Wk, sWk.h, sWk.l, D_ * D_ / 4);
  split_w<<<256, 256, 0, stream>>>(Wv, sWv.h, sWv.l, D_ * D_ / 4);
  split_w<<<256, 256, 0, stream>>>(Wq, sWq.h, sWq.l, D_ * D_ / 4);
  gather_split<<<BS * D_ / 4 / 256, 256, 0, stream>>>(embed, seqs_id, sXemb.h, sXemb.l);

  // ---- input GEMMs ----
  mgemm<0, true, false, true, true, false><<<dim3(128, 8, 1), 256, 0, stream>>>(
      nullptr, sXemb.h, sXemb.l, nullptr, sWihF.h, sWihF.l, b_f, nullptr,
      GX, nullptr, nullptr, BS, G4, D_, D_, 0, 0, 0);
  mgemm<0, true, false, true, true, false><<<dim3(128, 8, 1), 256, 0, stream>>>(
      nullptr, sXemb.h, sXemb.l, nullptr, sWihB.h, sWihB.l, b_b, nullptr,
      GX + (size_t)BS * G4, nullptr, nullptr, BS, G4, D_, D_, 0, 0, 0);

  lstm_dist<<<64, 256, 0, stream>>>(GX, WF, seqs_len, sLstm.h, sLstm.l, ring64, ringF);
  asps_k<<<B_, 512, 0, stream>>>(sLstm.h, sLstm.l, asps_mask, asps_len, aspsb);

  for (int it = 0; it < 2; ++it) {
    const Split xin = (it == 0) ? sLstm : sX;
    mgemm<0, true, false, true, true, false><<<dim3(2, 2, B_), 256, 0, stream>>>(
        nullptr, xin.h, xin.l, nullptr, sLstm.h, sLstm.l, nullptr, nullptr,
        scoreF, nullptr, nullptr, S_, S_, D_, D_,
        (long)S_ * D_, (long)S_ * D_, (long)S_ * S_);
    softmax_rows<<<BS, 256, 0, stream>>>(scoreF, asps_mask, sScore.h, sScore.l);
    mgemm<0, false, false, true, true, true><<<dim3(2, 4, B_), 256, 0, stream>>>(
        nullptr, sScore.h, sScore.l, nullptr, sLstm.h, sLstm.l, nullptr, nullptr,
        nullptr, sAttn.h, sAttn.l, S_, D_, S_, D_,
        (long)S_ * S_, (long)S_ * D_, (long)S_ * D_);
    mgemm<0, true, false, true, true, false><<<dim3(128, 4, 1), 256, 0, stream>>>(
        nullptr, sAttn.h, sAttn.l, nullptr, sWcpt.h, sWcpt.l, b_cpt, nullptr,
        lin, nullptr, nullptr, BS, D_, D_, 2 * D_, 0, 0, 0);
    mgemm<1, true, true, true, true, false><<<dim3(128, 4, 1), 256, 0, stream>>>(
        nullptr, xin.h, xin.l, nullptr, sWcpt.h + D_, sWcpt.l + D_, nullptr, lin,
        lin, nullptr, nullptr, BS, D_, D_, 2 * D_, 0, 0, 0);
    mgemm<2, true, false, true, true, false><<<dim3(128, 4, 1), 256, 0, stream>>>(
        nullptr, xin.h, xin.l, nullptr, sWas.h, sWas.l, b_as, nullptr,
        scl, nullptr, nullptr, BS, D_, D_, D_, 0, 0, 0);
    xupdate<<<(BS * D_ / 4 + 255) / 256, 256, 0, stream>>>(
        xin.h, xin.l, (const float4*)scl, (const float4*)lin, sX.h, sX.l, BS * D_ / 4);
  }

  mgemm<0, true, false, true, true, false><<<dim3(128, 4, 1), 256, 0, stream>>>(
      nullptr, sX.h, sX.l, nullptr, sWk.h, sWk.l, bk, nullptr,
      Kp, nullptr, nullptr, BS, D_, D_, D_, 0, 0, 0);
  mgemm<0, true, false, true, true, false><<<dim3(128, 4, 1), 256, 0, stream>>>(
      nullptr, sX.h, sX.l, nullptr, sWv.h, sWv.l, bv, nullptr,
      Vp, nullptr, nullptr, BS, D_, D_, D_, 0, 0, 0);
  mgemm<0, true, false, false, true, false><<<dim3(1, 4, 1), 256, 0, stream>>>(
      aspsb, nullptr, nullptr, nullptr, sWq.h, sWq.l, bq, nullptr,
      qp, nullptr, nullptr, B_, D_, D_, D_, 0, 0, 0);

  zero_outv<<<B_ * D_ / 512, 512, 0, stream>>>(outv);
  final_sc_k<<<B_, 256, 0, stream>>>(qp, Kp, sent_mask, outsc);
  out_vec_k<<<dim3(B_, 8, 1), 512, 0, stream>>>(outsc, Vp, outv);
  logits_k<<<B_, 192, 0, stream>>>(outv, Wd, bd, logits);
}

// Round 13
// 1517.601 us; speedup vs baseline: 1.1297x; 1.1297x over previous
//
#include <hip/hip_runtime.h>
#include <math.h>

constexpr int B_ = 64, S_ = 256, D_ = 512, H_ = 256, NC_ = 3;
constexpr int BS = B_ * S_;     // 16384
constexpr int G4 = 4 * H_;      // 1024

typedef __attribute__((ext_vector_type(4))) float f32x4;
typedef __attribute__((ext_vector_type(8))) short s16x8;
typedef unsigned short u16;
typedef unsigned long long u64;

template<int ACT>
static __device__ __forceinline__ float activate(float v) {
  if constexpr (ACT == 1) return v > 0.f ? v : 0.f;
  else if constexpr (ACT == 2) return 1.f / (1.f + expf(-v));
  else return v;
}

static __device__ __forceinline__ u16 f2bf_rne(float f) {
  unsigned u = __float_as_uint(f);
  return (u16)((u + 0x7FFFu + ((u >> 16) & 1u)) >> 16);
}
static __device__ __forceinline__ float bf2f(u16 h) {
  return __uint_as_float(((unsigned)h) << 16);
}
static __device__ __forceinline__ void splitf(float f, u16& h, u16& l) {
  h = f2bf_rne(f);
  float r = f - bf2f(h);
  l = f2bf_rne(r);
}

// ---------------- split precompute kernels ----------------
__global__ __launch_bounds__(256) void split_w(
    const float* __restrict__ src, u16* __restrict__ h, u16* __restrict__ l, int n4)
{
  int i = blockIdx.x * 256 + threadIdx.x;
  if (i >= n4) return;
  float4 v = ((const float4*)src)[i];
  ushort4 hh, ll;
  splitf(v.x, hh.x, ll.x); splitf(v.y, hh.y, ll.y);
  splitf(v.z, hh.z, ll.z); splitf(v.w, hh.w, ll.w);
  ((ushort4*)h)[i] = hh;
  ((ushort4*)l)[i] = ll;
}

// Xemb[m][k] = embed[gidx[m]][k]  (split)
__global__ __launch_bounds__(256) void gather_split(
    const float* __restrict__ embed, const int* __restrict__ gidx,
    u16* __restrict__ h, u16* __restrict__ l)
{
  int i = blockIdx.x * 256 + threadIdx.x;   // over BS*D/4
  if (i >= BS * D_ / 4) return;
  int r = i >> 7;            // row (D/4 = 128 float4 per row)
  int c = (i & 127) << 2;
  float4 v = *(const float4*)(embed + (size_t)gidx[r] * D_ + c);
  ushort4 hh, ll;
  splitf(v.x, hh.x, ll.x); splitf(v.y, hh.y, ll.y);
  splitf(v.z, hh.z, ll.z); splitf(v.w, hh.w, ll.w);
  ((ushort4*)h)[i] = hh;
  ((ushort4*)l)[i] = ll;
}

// ---------------- split-bf16 MFMA GEMM, 128x128 tile ----------------
// A2: A rows are [A (k<ksp) | A2 (k>=ksp)] concatenated along k (both split MxKsp)
template<int ACT, bool BT, bool ADDC, bool ASPL, bool BSPL, bool OSPL, bool A2>
__global__ __launch_bounds__(256) void mgemm(
    const float* __restrict__ Af, const u16* __restrict__ Ah, const u16* __restrict__ Al,
    const u16* __restrict__ Ah2, const u16* __restrict__ Al2,
    const float* __restrict__ Bf, const u16* __restrict__ Bh, const u16* __restrict__ Bl,
    const float* __restrict__ bias, const float* __restrict__ Cin,
    float* __restrict__ Co, u16* __restrict__ Oh, u16* __restrict__ Ol,
    int M, int N, int K, int ldb, long sA, long sB, long sC, int ksp)
{
  __shared__ u16 AH[128][40];
  __shared__ u16 AL[128][40];
  __shared__ u16 BH[128][40];
  __shared__ u16 BL[128][40];

  const int tid = threadIdx.x;
  const int w = tid >> 6, l = tid & 63;
  const int m0 = blockIdx.x * 128, n0 = blockIdx.y * 128;
  const long zA = (long)blockIdx.z * sA;
  const long zB = (long)blockIdx.z * sB;
  const long zC = (long)blockIdx.z * sC;

  f32x4 acc[2][8];
  #pragma unroll
  for (int i = 0; i < 2; ++i)
    #pragma unroll
    for (int j = 0; j < 8; ++j) acc[i][j] = (f32x4){0.f, 0.f, 0.f, 0.f};

  const int ar = tid >> 1, ahh = tid & 1;
  const int bk = tid >> 3, bnq = tid & 7;
  const int lr = l & 15, lk = (l >> 4) * 8;

  for (int kt = 0; kt < K; kt += 32) {
    {
      int m = m0 + ar;
      if constexpr (ASPL) {
        const u16* srcH = Ah;
        const u16* srcL = Al;
        int kc = kt, kspan = K;
        if constexpr (A2) {
          if (kt >= ksp) { srcH = Ah2; srcL = Al2; kc = kt - ksp; }
          kspan = ksp;
        }
        s16x8 h0 = (s16x8)0, h1 = (s16x8)0, l0 = (s16x8)0, l1 = (s16x8)0;
        if (m < M) {
          const u16* ph = srcH + zA + (size_t)m * kspan + kc + ahh * 16;
          const u16* pl = srcL + zA + (size_t)m * kspan + kc + ahh * 16;
          h0 = *(const s16x8*)ph; h1 = *(const s16x8*)(ph + 8);
          l0 = *(const s16x8*)pl; l1 = *(const s16x8*)(pl + 8);
        }
        *(s16x8*)&AH[ar][ahh * 16] = h0; *(s16x8*)&AH[ar][ahh * 16 + 8] = h1;
        *(s16x8*)&AL[ar][ahh * 16] = l0; *(s16x8*)&AL[ar][ahh * 16 + 8] = l1;
      } else {
        float vv[16];
        if (m < M) {
          const float* pf = Af + zA + (size_t)m * K + kt + ahh * 16;
          #pragma unroll
          for (int c = 0; c < 4; ++c) {
            float4 v = ((const float4*)pf)[c];
            vv[c * 4] = v.x; vv[c * 4 + 1] = v.y; vv[c * 4 + 2] = v.z; vv[c * 4 + 3] = v.w;
          }
        } else {
          #pragma unroll
          for (int c = 0; c < 16; ++c) vv[c] = 0.f;
        }
        u16 hh[16], ll[16];
        #pragma unroll
        for (int c = 0; c < 16; ++c) splitf(vv[c], hh[c], ll[c]);
        *(s16x8*)&AH[ar][ahh * 16] = *(s16x8*)&hh[0];
        *(s16x8*)&AH[ar][ahh * 16 + 8] = *(s16x8*)&hh[8];
        *(s16x8*)&AL[ar][ahh * 16] = *(s16x8*)&ll[0];
        *(s16x8*)&AL[ar][ahh * 16 + 8] = *(s16x8*)&ll[8];
      }
    }
    if constexpr (BT) {
      if constexpr (BSPL) {
        const u16* ph = Bh + zB + (size_t)(n0 + ar) * ldb + kt + ahh * 16;
        const u16* pl = Bl + zB + (size_t)(n0 + ar) * ldb + kt + ahh * 16;
        *(s16x8*)&BH[ar][ahh * 16] = *(const s16x8*)ph;
        *(s16x8*)&BH[ar][ahh * 16 + 8] = *(const s16x8*)(ph + 8);
        *(s16x8*)&BL[ar][ahh * 16] = *(const s16x8*)pl;
        *(s16x8*)&BL[ar][ahh * 16 + 8] = *(const s16x8*)(pl + 8);
      } else {
        const float* pf = Bf + zB + (size_t)(n0 + ar) * ldb + kt + ahh * 16;
        float vv[16];
        #pragma unroll
        for (int c = 0; c < 4; ++c) {
          float4 v = ((const float4*)pf)[c];
          vv[c * 4] = v.x; vv[c * 4 + 1] = v.y; vv[c * 4 + 2] = v.z; vv[c * 4 + 3] = v.w;
        }
        u16 hh[16], ll[16];
        #pragma unroll
        for (int c = 0; c < 16; ++c) splitf(vv[c], hh[c], ll[c]);
        *(s16x8*)&BH[ar][ahh * 16] = *(s16x8*)&hh[0];
        *(s16x8*)&BH[ar][ahh * 16 + 8] = *(s16x8*)&hh[8];
        *(s16x8*)&BL[ar][ahh * 16] = *(s16x8*)&ll[0];
        *(s16x8*)&BL[ar][ahh * 16 + 8] = *(s16x8*)&ll[8];
      }
    } else {
      const u16* ph = Bh + zB + (size_t)(kt + bk) * ldb + n0 + bnq * 16;
      const u16* pl = Bl + zB + (size_t)(kt + bk) * ldb + n0 + bnq * 16;
      s16x8 h8a = *(const s16x8*)ph, h8b = *(const s16x8*)(ph + 8);
      s16x8 l8a = *(const s16x8*)pl, l8b = *(const s16x8*)(pl + 8);
      #pragma unroll
      for (int jj = 0; jj < 8; ++jj) {
        BH[bnq * 16 + jj][bk] = (u16)h8a[jj];
        BH[bnq * 16 + 8 + jj][bk] = (u16)h8b[jj];
        BL[bnq * 16 + jj][bk] = (u16)l8a[jj];
        BL[bnq * 16 + 8 + jj][bk] = (u16)l8b[jj];
      }
    }
    __syncthreads();

    s16x8 afh[2], afl[2];
    #pragma unroll
    for (int i = 0; i < 2; ++i) {
      afh[i] = *(const s16x8*)&AH[w * 32 + i * 16 + lr][lk];
      afl[i] = *(const s16x8*)&AL[w * 32 + i * 16 + lr][lk];
    }
    #pragma unroll
    for (int j = 0; j < 8; ++j) {
      s16x8 bfh = *(const s16x8*)&BH[j * 16 + lr][lk];
      s16x8 bfl = *(const s16x8*)&BL[j * 16 + lr][lk];
      #pragma unroll
      for (int i = 0; i < 2; ++i) {
        acc[i][j] = __builtin_amdgcn_mfma_f32_16x16x32_bf16(afl[i], bfh, acc[i][j], 0, 0, 0);
        acc[i][j] = __builtin_amdgcn_mfma_f32_16x16x32_bf16(afh[i], bfl, acc[i][j], 0, 0, 0);
        acc[i][j] = __builtin_amdgcn_mfma_f32_16x16x32_bf16(afh[i], bfh, acc[i][j], 0, 0, 0);
      }
    }
    __syncthreads();
  }

  const int rl = (l >> 4) * 4;
  #pragma unroll
  for (int j = 0; j < 8; ++j) {
    int n = n0 + j * 16 + lr;
    float bv = bias ? bias[n] : 0.f;
    #pragma unroll
    for (int i = 0; i < 2; ++i) {
      #pragma unroll
      for (int e = 0; e < 4; ++e) {
        int m = m0 + w * 32 + i * 16 + rl + e;
        if (m < M) {
          float v = acc[i][j][e] + bv;
          if constexpr (ADDC) v += Cin[zC + (size_t)m * N + n];
          v = activate<ACT>(v);
          if constexpr (OSPL) {
            u16 hh, ll; splitf(v, hh, ll);
            Oh[zC + (size_t)m * N + n] = hh;
            Ol[zC + (size_t)m * N + n] = ll;
          } else {
            Co[zC + (size_t)m * N + n] = v;
          }
        }
      }
    }
  }
}

// ---------------- distributed LSTM (R9/R11-validated version) ----------------
// WF layout: q = (((dir*8+j)*4+w)*8+kt)*2+nt : hi at q*1024 + lane*8, lo at +512
__global__ __launch_bounds__(256) void wf_prep(
    const float* __restrict__ Wf, const float* __restrict__ Wb, u16* __restrict__ WF)
{
  int gid = blockIdx.x * 256 + threadIdx.x;   // 65536
  int lane = gid & 63;
  int nt = (gid >> 6) & 1;
  int kt = (gid >> 7) & 7;
  int w  = (gid >> 10) & 3;
  int j  = (gid >> 12) & 7;
  int dir = gid >> 15;
  const float* W = dir ? Wb : Wf;
  int r = w * 256 + j * 32 + nt * 16 + (lane & 15);
  int kb = kt * 32 + (lane >> 4) * 8;
  const float* src = W + (size_t)r * H_ + kb;
  u16 hh[8], ll[8];
  #pragma unroll
  for (int c = 0; c < 2; ++c) {
    float4 v = ((const float4*)src)[c];
    splitf(v.x, hh[c*4+0], ll[c*4+0]); splitf(v.y, hh[c*4+1], ll[c*4+1]);
    splitf(v.z, hh[c*4+2], ll[c*4+2]); splitf(v.w, hh[c*4+3], ll[c*4+3]);
  }
  size_t off = (size_t)(gid >> 6) * 1024 + (size_t)lane * 8;
  *(s16x8*)(WF + off)       = *(s16x8*)&hh[0];
  *(s16x8*)(WF + off + 512) = *(s16x8*)&ll[0];
}

// re-tag the entire ring to generation 3 (invalid for the first reads)
__global__ __launch_bounds__(256) void ring_init(u64* __restrict__ ring64)
{
  int i = blockIdx.x * 256 + threadIdx.x;   // 65536
  __hip_atomic_store(&ring64[i], (u64)3, __ATOMIC_RELAXED, __HIP_MEMORY_SCOPE_AGENT);
}

// grid 64: grp = bid&7 (dir*4+bg), j = bid>>3. 256 threads (4 waves).
// Self-validating tagged ring: u64 word = {fp32 h1 | fp32 h0 with 2-bit gen tag
// in mantissa LSBs}. gen = (t>>2)&3, slot = t&3. Poll data words directly.
__global__ __launch_bounds__(256, 1) void lstm_dist(
    const float* __restrict__ GX, const u16* __restrict__ WF,
    const int* __restrict__ lens, u16* __restrict__ outH, u16* __restrict__ outL,
    u64* __restrict__ ring64)
{
  const int bid = blockIdx.x;
  const int grp = bid & 7;
  const int j   = bid >> 3;
  const int dir = grp >> 2;
  const int bg  = grp & 3;
  const int b0g = bg * 16;
  const int tid = threadIdx.x;
  const int w = tid >> 6, l = tid & 63;

  const float* gx = GX + (size_t)dir * ((size_t)BS * G4);

  __shared__ int slen[16];
  __shared__ __align__(16) u16 AHs[16][264];
  __shared__ __align__(16) u16 ALs[16][264];
  __shared__ float act[2][4][16][33];    // double-buffered by t&1
  if (tid < 16) slen[tid] = lens[b0g + tid];
  __syncthreads();

  s16x8 wh[8][2], wl[8][2];
  #pragma unroll
  for (int kt = 0; kt < 8; ++kt)
    #pragma unroll
    for (int nt = 0; nt < 2; ++nt) {
      size_t q = ((size_t)(((dir * 8 + j) * 4 + w) * 8 + kt) * 2 + nt);
      const u16* p = WF + q * 1024 + (size_t)l * 8;
      wh[kt][nt] = *(const s16x8*)p;
      wl[kt][nt] = *(const s16x8*)(p + 512);
    }

  const int ub = tid >> 4;
  const int uu = (tid & 15) * 2;
  const int len_b = slen[ub];
  float c0s = 0.f, c1s = 0.f, h0s = 0.f, h1s = 0.f;

  const int lr = l & 15, lkb = (l >> 4) * 8;

  for (int t = 0; t < S_; ++t) {
    float gxv[2][4];
    #pragma unroll
    for (int nt = 0; nt < 2; ++nt)
      #pragma unroll
      for (int e = 0; e < 4; ++e) {
        int b = (l >> 4) * 4 + e;
        int len = slen[b];
        int pos = dir ? (t < len ? len - 1 - t : t) : t;
        gxv[nt][e] = gx[(size_t)((b0g + b) * S_ + pos) * G4 + (w * 256 + j * 32 + nt * 16 + lr)];
      }

    f32x4 acc[2];
    acc[0] = (f32x4){0.f, 0.f, 0.f, 0.f};
    acc[1] = (f32x4){0.f, 0.f, 0.f, 0.f};

    if (t > 0) {
      const unsigned gen = (unsigned)(((t - 1) >> 2) & 3);
      const int slot = (t - 1) & 3;
      u64* rb = ring64 + ((size_t)slot * 8 + grp) * (16 * 128);
      u64 v[8];
      unsigned need = 0xFFu;
      do {
        unsigned nn = 0;
        #pragma unroll
        for (int k = 0; k < 8; ++k)
          if ((need >> k) & 1)
            v[k] = __hip_atomic_load(&rb[k * 256 + tid], __ATOMIC_RELAXED, __HIP_MEMORY_SCOPE_AGENT);
        #pragma unroll
        for (int k = 0; k < 8; ++k)
          if (((need >> k) & 1) && ((unsigned)v[k] & 3u) != gen) nn |= 1u << k;
        need = nn;
      } while (need);
      #pragma unroll
      for (int k = 0; k < 8; ++k) {
        int idx = k * 256 + tid;
        int b = idx >> 7, p = idx & 127;
        float f0 = __uint_as_float((unsigned)v[k] & ~3u);
        float f1 = __uint_as_float((unsigned)(v[k] >> 32));
        u16 hh0, ll0, hh1, ll1;
        splitf(f0, hh0, ll0); splitf(f1, hh1, ll1);
        *(unsigned*)&AHs[b][2 * p] = (unsigned)hh0 | ((unsigned)hh1 << 16);
        *(unsigned*)&ALs[b][2 * p] = (unsigned)ll0 | ((unsigned)ll1 << 16);
      }
      __syncthreads();
      #pragma unroll
      for (int kt = 0; kt < 8; ++kt) {
        s16x8 ah = *(const s16x8*)&AHs[lr][kt * 32 + lkb];
        s16x8 al = *(const s16x8*)&ALs[lr][kt * 32 + lkb];
        #pragma unroll
        for (int nt = 0; nt < 2; ++nt) {
          acc[nt] = __builtin_amdgcn_mfma_f32_16x16x32_bf16(al, wh[kt][nt], acc[nt], 0, 0, 0);
          acc[nt] = __builtin_amdgcn_mfma_f32_16x16x32_bf16(ah, wl[kt][nt], acc[nt], 0, 0, 0);
          acc[nt] = __builtin_amdgcn_mfma_f32_16x16x32_bf16(ah, wh[kt][nt], acc[nt], 0, 0, 0);
        }
      }
    }

    const int pb = t & 1;
    #pragma unroll
    for (int nt = 0; nt < 2; ++nt)
      #pragma unroll
      for (int e = 0; e < 4; ++e) {
        float v = acc[nt][e] + gxv[nt][e];
        v = (w == 2) ? tanhf(v) : 1.f / (1.f + expf(-v));
        act[pb][w][(l >> 4) * 4 + e][nt * 16 + lr] = v;
      }
    __syncthreads();

    {
      int pos = dir ? (t < len_b ? len_b - 1 - t : t) : t;
      bool valid = t < len_b;
      float i0 = act[pb][0][ub][uu],     f0 = act[pb][1][ub][uu],     g0 = act[pb][2][ub][uu],     o0 = act[pb][3][ub][uu];
      float i1 = act[pb][0][ub][uu + 1], f1 = act[pb][1][ub][uu + 1], g1 = act[pb][2][ub][uu + 1], o1 = act[pb][3][ub][uu + 1];
      float cn0 = fmaf(f0, c0s, i0 * g0), cn1 = fmaf(f1, c1s, i1 * g1);
      float hn0 = o0 * tanhf(cn0), hn1 = o1 * tanhf(cn1);
      if (valid) { c0s = cn0; h0s = hn0; c1s = cn1; h1s = hn1; }
      unsigned gen = (unsigned)((t >> 2) & 3);
      unsigned a0 = (__float_as_uint(h0s) & ~3u) | gen;
      unsigned a1 = __float_as_uint(h1s);
      u64 word = ((u64)a1 << 32) | (u64)a0;
      const int slot = t & 3;
      size_t ridx = ((size_t)slot * 8 + grp) * (16 * 128) + (size_t)ub * 128 + j * 16 + (tid & 15);
      __hip_atomic_store(&ring64[ridx], word, __ATOMIC_RELAXED, __HIP_MEMORY_SCOPE_AGENT);
      float ov0 = valid ? hn0 : 0.f, ov1 = valid ? hn1 : 0.f;
      u16 oh0, qq0, oh1, qq1;
      splitf(ov0, oh0, qq0); splitf(ov1, oh1, qq1);
      size_t obase = (size_t)((b0g + ub) * S_ + pos) * (2 * H_) + dir * H_ + j * 32 + uu;
      *(ushort2*)&outH[obase] = make_ushort2(oh0, oh1);
      *(ushort2*)&outL[obase] = make_ushort2(qq0, qq1);
    }
    // no trailing barrier: act double-buffered; AHs writes gated by next
    // iteration's post-staging barrier.
  }
}

// span-based aspect mean: only the <=5 rows with amask==0 contribute
__global__ __launch_bounds__(512) void asps_k(
    const u16* __restrict__ lh, const u16* __restrict__ ll,
    const float* __restrict__ amask, const int* __restrict__ alen, float* __restrict__ asps)
{
  int b = blockIdx.x, tid = threadIdx.x;
  __shared__ int sstart;
  if (tid == 0) sstart = S_;
  __syncthreads();
  if (tid < S_ && amask[b * S_ + tid] == 0.f) atomicMin(&sstart, tid);
  __syncthreads();
  const int start = sstart;
  const int len = alen[b];
  float acc = 0.f;
  for (int k = 0; k < len; ++k) {
    size_t i = ((size_t)(b * S_ + start + k)) * D_ + tid;
    acc += bf2f(lh[i]) + bf2f(ll[i]);
  }
  asps[b * D_ + tid] = acc / (float)len;
}

__global__ __launch_bounds__(256) void softmax_rows(
    const float* __restrict__ p_, const float* __restrict__ mask,
    u16* __restrict__ ph, u16* __restrict__ pl)
{
  const int row = blockIdx.x;
  const int b = row >> 8;
  const int tid = threadIdx.x;
  const float* p = p_ + (size_t)row * S_;
  float v = p[tid] + mask[(b << 8) | tid];
  float m = v;
  #pragma unroll
  for (int off = 32; off > 0; off >>= 1) m = fmaxf(m, __shfl_xor(m, off));
  __shared__ float r1[4];
  __shared__ float r2[4];
  const int w = tid >> 6, l = tid & 63;
  if (l == 0) r1[w] = m;
  __syncthreads();
  m = fmaxf(fmaxf(r1[0], r1[1]), fmaxf(r1[2], r1[3]));
  float e = expf(v - m);
  float s = e;
  #pragma unroll
  for (int off = 32; off > 0; off >>= 1) s += __shfl_xor(s, off);
  if (l == 0) r2[w] = s;
  __syncthreads();
  s = r2[0] + r2[1] + r2[2] + r2[3];
  float o = e / s;
  u16 hh, ll; splitf(o, hh, ll);
  ph[(size_t)row * S_ + tid] = hh;
  pl[(size_t)row * S_ + tid] = ll;
}

__global__ __launch_bounds__(256) void xupdate(
    const u16* __restrict__ xh, const u16* __restrict__ xl,
    const float4* __restrict__ sc, const float4* __restrict__ lin,
    u16* __restrict__ oh, u16* __restrict__ ol, int n4)
{
  int i = blockIdx.x * 256 + threadIdx.x;
  if (i >= n4) return;
  ushort4 h4 = ((const ushort4*)xh)[i];
  ushort4 l4 = ((const ushort4*)xl)[i];
  float4 s = sc[i], lv = lin[i];
  float x0 = bf2f(h4.x) + bf2f(l4.x);
  float x1 = bf2f(h4.y) + bf2f(l4.y);
  float x2 = bf2f(h4.z) + bf2f(l4.z);
  float x3 = bf2f(h4.w) + bf2f(l4.w);
  float o0 = s.x * lv.x + (1.f - s.x) * x0;
  float o1 = s.y * lv.y + (1.f - s.y) * x1;
  float o2 = s.z * lv.z + (1.f - s.z) * x2;
  float o3 = s.w * lv.w + (1.f - s.w) * x3;
  ushort4 hh, ll;
  splitf(o0, hh.x, ll.x); splitf(o1, hh.y, ll.y);
  splitf(o2, hh.z, ll.z); splitf(o3, hh.w, ll.w);
  ((ushort4*)oh)[i] = hh;
  ((ushort4*)ol)[i] = ll;
}

__global__ __launch_bounds__(256) void final_sc_k(
    const float* __restrict__ Qp, const float* __restrict__ Kp,
    const float* __restrict__ smask, float* __restrict__ outsc)
{
  int b = blockIdx.x, tid = threadIdx.x;
  __shared__ float q[D_];
  q[tid] = Qp[b * D_ + tid];
  q[tid + 256] = Qp[b * D_ + tid + 256];
  __syncthreads();
  const float4* kr = (const float4*)(Kp + ((size_t)(b * S_ + tid)) * D_);
  float acc = 0.f;
  #pragma unroll 4
  for (int d = 0; d < D_ / 4; ++d) {
    float4 kv = kr[d];
    acc += q[4 * d] * kv.x + q[4 * d + 1] * kv.y + q[4 * d + 2] * kv.z + q[4 * d + 3] * kv.w;
  }
  float v = acc / sqrtf((float)D_) + smask[b * S_ + tid];
  float m = v;
  #pragma unroll
  for (int off = 32; off > 0; off >>= 1) m = fmaxf(m, __shfl_xor(m, off));
  __shared__ float r1[4];
  __shared__ float r2[4];
  const int w = tid >> 6, l = tid & 63;
  if (l == 0) r1[w] = m;
  __syncthreads();
  m = fmaxf(fmaxf(r1[0], r1[1]), fmaxf(r1[2], r1[3]));
  float e = expf(v - m);
  float s = e;
  #pragma unroll
  for (int off = 32; off > 0; off >>= 1) s += __shfl_xor(s, off);
  if (l == 0) r2[w] = s;
  __syncthreads();
  s = r2[0] + r2[1] + r2[2] + r2[3];
  outsc[b * S_ + tid] = e / s;
}

__global__ __launch_bounds__(512) void zero_outv(float* __restrict__ p)
{
  p[blockIdx.x * 512 + threadIdx.x] = 0.f;
}

// k-split weighted sum: grid (B, 8), each block sums a 32-k slice, atomicAdd.
__global__ __launch_bounds__(512) void out_vec_k(
    const float* __restrict__ sc, const float* __restrict__ Vp, float* __restrict__ outv)
{
  int b = blockIdx.x, d = threadIdx.x;
  int k0 = blockIdx.y * 32;
  __shared__ float s[32];
  if (d < 32) s[d] = sc[b * S_ + k0 + d];
  __syncthreads();
  float acc = 0.f;
  #pragma unroll
  for (int k = 0; k < 32; ++k)
    acc = fmaf(s[k], Vp[((size_t)(b * S_ + k0 + k)) * D_ + d], acc);
  atomicAdd(&outv[b * D_ + d], acc);
}

__global__ __launch_bounds__(192) void logits_k(
    const float* __restrict__ outv, const float* __restrict__ Wd,
    const float* __restrict__ bd, float* __restrict__ out)
{
  int b = blockIdx.x;
  int c = threadIdx.x >> 6, l = threadIdx.x & 63;
  float acc = 0.f;
  for (int d = l; d < D_; d += 64) acc = fmaf(outv[b * D_ + d], Wd[c * D_ + d], acc);
  #pragma unroll
  for (int off = 32; off > 0; off >>= 1) acc += __shfl_down(acc, off);
  if (l == 0) out[b * NC_ + c] = acc + bd[c];
}

extern "C" void kernel_launch(void* const* d_in, const int* in_sizes, int n_in,
                              void* d_out, int out_size, void* d_ws, size_t ws_size,
                              hipStream_t stream)
{
  const int*   seqs_id   = (const int*)d_in[0];
  const int*   seqs_len  = (const int*)d_in[1];
  const int*   asps_len  = (const int*)d_in[2];
  const float* asps_mask = (const float*)d_in[3];
  const float* sent_mask = (const float*)d_in[4];
  const float* embed     = (const float*)d_in[5];
  const float* Wih_f     = (const float*)d_in[6];
  const float* Whh_f     = (const float*)d_in[7];
  const float* b_f       = (const float*)d_in[8];
  const float* Wih_b     = (const float*)d_in[9];
  const float* Whh_b     = (const float*)d_in[10];
  const float* b_b       = (const float*)d_in[11];
  const float* W_cpt     = (const float*)d_in[12];
  const float* b_cpt     = (const float*)d_in[13];
  const float* W_as      = (const float*)d_in[14];
  const float* b_as      = (const float*)d_in[15];
  const float* Wq        = (const float*)d_in[16];
  const float* bq        = (const float*)d_in[17];
  const float* Wk        = (const float*)d_in[18];
  const float* bk        = (const float*)d_in[19];
  const float* Wv        = (const float*)d_in[20];
  const float* bv        = (const float*)d_in[21];
  const float* Wd        = (const float*)d_in[22];
  const float* bd        = (const float*)d_in[23];

  float* w = (float*)d_ws;
  size_t off = 0;
  auto alloc = [&](size_t words) { size_t o = off; off += words; return o; };
  struct Split { u16* h; u16* l; };
  auto salloc = [&](size_t n) {
    size_t o = alloc(n);
    Split s; s.h = (u16*)(w + o); s.l = (u16*)(w + o) + n; return s;
  };

  // ---- persistent ----
  const size_t off_wf   = alloc(524288);            // WF: 2 MB (1M u16)
  const size_t off_ring = alloc(131072);            // ring64: 64K u64 = 512 KB
  Split sWihF = salloc(4ul * H_ * D_);
  Split sWihB = salloc(4ul * H_ * D_);
  Split sWcpt = salloc((size_t)D_ * 2 * D_);
  Split sWas  = salloc((size_t)D_ * D_);
  Split sWk   = salloc((size_t)D_ * D_);
  Split sWv   = salloc((size_t)D_ * D_);
  Split sWq   = salloc((size_t)D_ * D_);
  Split sLstm = salloc((size_t)BS * D_);
  const size_t off_asps = alloc((size_t)B_ * D_);
  const size_t off_qp   = alloc((size_t)B_ * D_);
  const size_t off_outv = alloc((size_t)B_ * D_);

  // ---- dynamic region ----
  const size_t dyn0 = off;
  Split sXemb; sXemb.h = (u16*)(w + dyn0); sXemb.l = sXemb.h + (size_t)BS * D_;
  float* GX = w + dyn0 + (size_t)BS * D_;
  size_t p2 = dyn0;
  float* scoreF = w + p2;                 p2 += (size_t)B_ * S_ * S_;
  Split sScore; sScore.h = (u16*)(w + p2); sScore.l = sScore.h + (size_t)B_ * S_ * S_; p2 += (size_t)B_ * S_ * S_;
  Split sAttn;  sAttn.h  = (u16*)(w + p2); sAttn.l  = sAttn.h + (size_t)BS * D_;       p2 += (size_t)BS * D_;
  float* lin = w + p2;                    p2 += (size_t)BS * D_;
  float* scl = w + p2;                    p2 += (size_t)BS * D_;
  Split sX;     sX.h     = (u16*)(w + p2); sX.l     = sX.h + (size_t)BS * D_;           p2 += (size_t)BS * D_;

  u16* WF      = (u16*)(w + off_wf);
  u64* ring64  = (u64*)(w + off_ring);
  float* aspsb = w + off_asps;
  float* qp    = w + off_qp;
  float* outv  = w + off_outv;
  float* Kp    = (float*)sAttn.h;
  float* Vp    = lin;
  float* logits = (float*)d_out;
  float* outsc  = (float*)d_out + B_ * NC_;

  // ---- prep ----
  ring_init<<<256, 256, 0, stream>>>(ring64);
  wf_prep<<<256, 256, 0, stream>>>(Whh_f, Whh_b, WF);
  split_w<<<512, 256, 0, stream>>>(Wih_f, sWihF.h, sWihF.l, H_ * D_);
  split_w<<<512, 256, 0, stream>>>(Wih_b, sWihB.h, sWihB.l, H_ * D_);
  split_w<<<512, 256, 0, stream>>>(W_cpt, sWcpt.h, sWcpt.l, D_ * 2 * D_ / 4);
  split_w<<<256, 256, 0, stream>>>(W_as, sWas.h, sWas.l, D_ * D_ / 4);
  split_w<<<256, 256, 0, stream>>>(Wk, sWk.h, sWk.l, D_ * D_ / 4);
  split_w<<<256, 256, 0, stream>>>(Wv, sWv.h, sWv.l, D_ * D_ / 4);
  split_w<<<256, 256, 0, stream>>>(Wq, sWq.h, sWq.l, D_ * D_ / 4);
  gather_split<<<BS * D_ / 4 / 256, 256, 0, stream>>>(embed, seqs_id, sXemb.h, sXemb.l);

  // ---- input GEMMs ----
  mgemm<0, true, false, true, true, false, false><<<dim3(128, 8, 1), 256, 0, stream>>>(
      nullptr, sXemb.h, sXemb.l, nullptr, nullptr, nullptr, sWihF.h, sWihF.l, b_f, nullptr,
      GX, nullptr, nullptr, BS, G4, D_, D_, 0, 0, 0, 0);
  mgemm<0, true, false, true, true, false, false><<<dim3(128, 8, 1), 256, 0, stream>>>(
      nullptr, sXemb.h, sXemb.l, nullptr, nullptr, nullptr, sWihB.h, sWihB.l, b_b, nullptr,
      GX + (size_t)BS * G4, nullptr, nullptr, BS, G4, D_, D_, 0, 0, 0, 0);

  lstm_dist<<<64, 256, 0, stream>>>(GX, WF, seqs_len, sLstm.h, sLstm.l, ring64);
  asps_k<<<B_, 512, 0, stream>>>(sLstm.h, sLstm.l, asps_mask, asps_len, aspsb);

  for (int it = 0; it < 2; ++it) {
    const Split xin = (it == 0) ? sLstm : sX;
    mgemm<0, true, false, true, true, false, false><<<dim3(2, 2, B_), 256, 0, stream>>>(
        nullptr, xin.h, xin.l, nullptr, nullptr, nullptr, sLstm.h, sLstm.l, nullptr, nullptr,
        scoreF, nullptr, nullptr, S_, S_, D_, D_,
        (long)S_ * D_, (long)S_ * D_, (long)S_ * S_, 0);
    softmax_rows<<<BS, 256, 0, stream>>>(scoreF, asps_mask, sScore.h, sScore.l);
    mgemm<0, false, false, true, true, true, false><<<dim3(2, 4, B_), 256, 0, stream>>>(
        nullptr, sScore.h, sScore.l, nullptr, nullptr, nullptr, sLstm.h, sLstm.l, nullptr, nullptr,
        nullptr, sAttn.h, sAttn.l, S_, D_, S_, D_,
        (long)S_ * S_, (long)S_ * D_, (long)S_ * D_, 0);
    // lin = relu([attn | x] @ Wcpt^T + b)  -- fused dual-A, K=1024
    mgemm<1, true, false, true, true, false, true><<<dim3(128, 4, 1), 256, 0, stream>>>(
        nullptr, sAttn.h, sAttn.l, xin.h, xin.l, nullptr, sWcpt.h, sWcpt.l, b_cpt, nullptr,
        lin, nullptr, nullptr, BS, D_, 2 * D_, 2 * D_, 0, 0, 0, D_);
    mgemm<2, true, false, true, true, false, false><<<dim3(128, 4, 1), 256, 0, stream>>>(
        nullptr, xin.h, xin.l, nullptr, nullptr, nullptr, sWas.h, sWas.l, b_as, nullptr,
        scl, nullptr, nullptr, BS, D_, D_, D_, 0, 0, 0, 0);
    xupdate<<<(BS * D_ / 4 + 255) / 256, 256, 0, stream>>>(
        xin.h, xin.l, (const float4*)scl, (const float4*)lin, sX.h, sX.l, BS * D_ / 4);
  }

  mgemm<0, true, false, true, true, false, false><<<dim3(128, 4, 1), 256, 0, stream>>>(
      nullptr, sX.h, sX.l, nullptr, nullptr, nullptr, sWk.h, sWk.l, bk, nullptr,
      Kp, nullptr, nullptr, BS, D_, D_, D_, 0, 0, 0, 0);
  mgemm<0, true, false, true, true, false, false><<<dim3(128, 4, 1), 256, 0, stream>>>(
      nullptr, sX.h, sX.l, nullptr, nullptr, nullptr, sWv.h, sWv.l, bv, nullptr,
      Vp, nullptr, nullptr, BS, D_, D_, D_, 0, 0, 0, 0);
  mgemm<0, true, false, false, true, false, false><<<dim3(1, 4, 1), 256, 0, stream>>>(
      aspsb, nullptr, nullptr, nullptr, nullptr, nullptr, sWq.h, sWq.l, bq, nullptr,
      qp, nullptr, nullptr, B_, D_, D_, D_, 0, 0, 0, 0);

  zero_outv<<<B_ * D_ / 512, 512, 0, stream>>>(outv);
  final_sc_k<<<B_, 256, 0, stream>>>(qp, Kp, sent_mask, outsc);
  out_vec_k<<<dim3(B_, 8, 1), 512, 0, stream>>>(outsc, Vp, outv);
  logits_k<<<B_, 192, 0, stream>>>(outv, Wd, bd, logits);
}

// Round 14
// 1508.839 us; speedup vs baseline: 1.1362x; 1.0058x over previous
//
#include <hip/hip_runtime.h>
#include <math.h>

constexpr int B_ = 64, S_ = 256, D_ = 512, H_ = 256, NC_ = 3;
constexpr int BS = B_ * S_;     // 16384
constexpr int G4 = 4 * H_;      // 1024

typedef __attribute__((ext_vector_type(4))) float f32x4;
typedef __attribute__((ext_vector_type(8))) short s16x8;
typedef unsigned short u16;
typedef unsigned long long u64;

template<int ACT>
static __device__ __forceinline__ float activate(float v) {
  if constexpr (ACT == 1) return v > 0.f ? v : 0.f;
  else if constexpr (ACT == 2) return 1.f / (1.f + expf(-v));
  else return v;
}

static __device__ __forceinline__ u16 f2bf_rne(float f) {
  unsigned u = __float_as_uint(f);
  return (u16)((u + 0x7FFFu + ((u >> 16) & 1u)) >> 16);
}
static __device__ __forceinline__ float bf2f(u16 h) {
  return __uint_as_float(((unsigned)h) << 16);
}
static __device__ __forceinline__ void splitf(float f, u16& h, u16& l) {
  h = f2bf_rne(f);
  float r = f - bf2f(h);
  l = f2bf_rne(r);
}

// ---------------- split precompute kernels ----------------
__global__ __launch_bounds__(256) void split_w(
    const float* __restrict__ src, u16* __restrict__ h, u16* __restrict__ l, int n4)
{
  int i = blockIdx.x * 256 + threadIdx.x;
  if (i >= n4) return;
  float4 v = ((const float4*)src)[i];
  ushort4 hh, ll;
  splitf(v.x, hh.x, ll.x); splitf(v.y, hh.y, ll.y);
  splitf(v.z, hh.z, ll.z); splitf(v.w, hh.w, ll.w);
  ((ushort4*)h)[i] = hh;
  ((ushort4*)l)[i] = ll;
}

// Xemb[m][k] = embed[gidx[m]][k]  (split)
__global__ __launch_bounds__(256) void gather_split(
    const float* __restrict__ embed, const int* __restrict__ gidx,
    u16* __restrict__ h, u16* __restrict__ l)
{
  int i = blockIdx.x * 256 + threadIdx.x;   // over BS*D/4
  if (i >= BS * D_ / 4) return;
  int r = i >> 7;            // row (D/4 = 128 float4 per row)
  int c = (i & 127) << 2;
  float4 v = *(const float4*)(embed + (size_t)gidx[r] * D_ + c);
  ushort4 hh, ll;
  splitf(v.x, hh.x, ll.x); splitf(v.y, hh.y, ll.y);
  splitf(v.z, hh.z, ll.z); splitf(v.w, hh.w, ll.w);
  ((ushort4*)h)[i] = hh;
  ((ushort4*)l)[i] = ll;
}

// ---------------- split-bf16 MFMA GEMM, 128x128 tile ----------------
// A2: A rows are [A (k<ksp) | A2 (k>=ksp)] concatenated along k
// XUP: epilogue computes s=act(v); o = s*Cin + (1-s)*(Ah2+Al2); writes split Oh/Ol
template<int ACT, bool BT, bool ADDC, bool ASPL, bool BSPL, bool OSPL, bool A2, bool XUP>
__global__ __launch_bounds__(256) void mgemm(
    const float* __restrict__ Af, const u16* __restrict__ Ah, const u16* __restrict__ Al,
    const u16* __restrict__ Ah2, const u16* __restrict__ Al2,
    const float* __restrict__ Bf, const u16* __restrict__ Bh, const u16* __restrict__ Bl,
    const float* __restrict__ bias, const float* __restrict__ Cin,
    float* __restrict__ Co, u16* __restrict__ Oh, u16* __restrict__ Ol,
    int M, int N, int K, int ldb, long sA, long sB, long sC, int ksp)
{
  __shared__ u16 AH[128][40];
  __shared__ u16 AL[128][40];
  __shared__ u16 BH[128][40];
  __shared__ u16 BL[128][40];

  const int tid = threadIdx.x;
  const int w = tid >> 6, l = tid & 63;
  const int m0 = blockIdx.x * 128, n0 = blockIdx.y * 128;
  const long zA = (long)blockIdx.z * sA;
  const long zB = (long)blockIdx.z * sB;
  const long zC = (long)blockIdx.z * sC;

  f32x4 acc[2][8];
  #pragma unroll
  for (int i = 0; i < 2; ++i)
    #pragma unroll
    for (int j = 0; j < 8; ++j) acc[i][j] = (f32x4){0.f, 0.f, 0.f, 0.f};

  const int ar = tid >> 1, ahh = tid & 1;
  const int bk = tid >> 3, bnq = tid & 7;
  const int lr = l & 15, lk = (l >> 4) * 8;

  for (int kt = 0; kt < K; kt += 32) {
    {
      int m = m0 + ar;
      if constexpr (ASPL) {
        const u16* srcH = Ah;
        const u16* srcL = Al;
        int kc = kt, kspan = K;
        if constexpr (A2) {
          if (kt >= ksp) { srcH = Ah2; srcL = Al2; kc = kt - ksp; }
          kspan = ksp;
        }
        s16x8 h0 = (s16x8)0, h1 = (s16x8)0, l0 = (s16x8)0, l1 = (s16x8)0;
        if (m < M) {
          const u16* ph = srcH + zA + (size_t)m * kspan + kc + ahh * 16;
          const u16* pl = srcL + zA + (size_t)m * kspan + kc + ahh * 16;
          h0 = *(const s16x8*)ph; h1 = *(const s16x8*)(ph + 8);
          l0 = *(const s16x8*)pl; l1 = *(const s16x8*)(pl + 8);
        }
        *(s16x8*)&AH[ar][ahh * 16] = h0; *(s16x8*)&AH[ar][ahh * 16 + 8] = h1;
        *(s16x8*)&AL[ar][ahh * 16] = l0; *(s16x8*)&AL[ar][ahh * 16 + 8] = l1;
      } else {
        float vv[16];
        if (m < M) {
          const float* pf = Af + zA + (size_t)m * K + kt + ahh * 16;
          #pragma unroll
          for (int c = 0; c < 4; ++c) {
            float4 v = ((const float4*)pf)[c];
            vv[c * 4] = v.x; vv[c * 4 + 1] = v.y; vv[c * 4 + 2] = v.z; vv[c * 4 + 3] = v.w;
          }
        } else {
          #pragma unroll
          for (int c = 0; c < 16; ++c) vv[c] = 0.f;
        }
        u16 hh[16], ll[16];
        #pragma unroll
        for (int c = 0; c < 16; ++c) splitf(vv[c], hh[c], ll[c]);
        *(s16x8*)&AH[ar][ahh * 16] = *(s16x8*)&hh[0];
        *(s16x8*)&AH[ar][ahh * 16 + 8] = *(s16x8*)&hh[8];
        *(s16x8*)&AL[ar][ahh * 16] = *(s16x8*)&ll[0];
        *(s16x8*)&AL[ar][ahh * 16 + 8] = *(s16x8*)&ll[8];
      }
    }
    if constexpr (BT) {
      if constexpr (BSPL) {
        const u16* ph = Bh + zB + (size_t)(n0 + ar) * ldb + kt + ahh * 16;
        const u16* pl = Bl + zB + (size_t)(n0 + ar) * ldb + kt + ahh * 16;
        *(s16x8*)&BH[ar][ahh * 16] = *(const s16x8*)ph;
        *(s16x8*)&BH[ar][ahh * 16 + 8] = *(const s16x8*)(ph + 8);
        *(s16x8*)&BL[ar][ahh * 16] = *(const s16x8*)pl;
        *(s16x8*)&BL[ar][ahh * 16 + 8] = *(const s16x8*)(pl + 8);
      } else {
        const float* pf = Bf + zB + (size_t)(n0 + ar) * ldb + kt + ahh * 16;
        float vv[16];
        #pragma unroll
        for (int c = 0; c < 4; ++c) {
          float4 v = ((const float4*)pf)[c];
          vv[c * 4] = v.x; vv[c * 4 + 1] = v.y; vv[c * 4 + 2] = v.z; vv[c * 4 + 3] = v.w;
        }
        u16 hh[16], ll[16];
        #pragma unroll
        for (int c = 0; c < 16; ++c) splitf(vv[c], hh[c], ll[c]);
        *(s16x8*)&BH[ar][ahh * 16] = *(s16x8*)&hh[0];
        *(s16x8*)&BH[ar][ahh * 16 + 8] = *(s16x8*)&hh[8];
        *(s16x8*)&BL[ar][ahh * 16] = *(s16x8*)&ll[0];
        *(s16x8*)&BL[ar][ahh * 16 + 8] = *(s16x8*)&ll[8];
      }
    } else {
      const u16* ph = Bh + zB + (size_t)(kt + bk) * ldb + n0 + bnq * 16;
      const u16* pl = Bl + zB + (size_t)(kt + bk) * ldb + n0 + bnq * 16;
      s16x8 h8a = *(const s16x8*)ph, h8b = *(const s16x8*)(ph + 8);
      s16x8 l8a = *(const s16x8*)pl, l8b = *(const s16x8*)(pl + 8);
      #pragma unroll
      for (int jj = 0; jj < 8; ++jj) {
        BH[bnq * 16 + jj][bk] = (u16)h8a[jj];
        BH[bnq * 16 + 8 + jj][bk] = (u16)h8b[jj];
        BL[bnq * 16 + jj][bk] = (u16)l8a[jj];
        BL[bnq * 16 + 8 + jj][bk] = (u16)l8b[jj];
      }
    }
    __syncthreads();

    s16x8 afh[2], afl[2];
    #pragma unroll
    for (int i = 0; i < 2; ++i) {
      afh[i] = *(const s16x8*)&AH[w * 32 + i * 16 + lr][lk];
      afl[i] = *(const s16x8*)&AL[w * 32 + i * 16 + lr][lk];
    }
    #pragma unroll
    for (int j = 0; j < 8; ++j) {
      s16x8 bfh = *(const s16x8*)&BH[j * 16 + lr][lk];
      s16x8 bfl = *(const s16x8*)&BL[j * 16 + lr][lk];
      #pragma unroll
      for (int i = 0; i < 2; ++i) {
        acc[i][j] = __builtin_amdgcn_mfma_f32_16x16x32_bf16(afl[i], bfh, acc[i][j], 0, 0, 0);
        acc[i][j] = __builtin_amdgcn_mfma_f32_16x16x32_bf16(afh[i], bfl, acc[i][j], 0, 0, 0);
        acc[i][j] = __builtin_amdgcn_mfma_f32_16x16x32_bf16(afh[i], bfh, acc[i][j], 0, 0, 0);
      }
    }
    __syncthreads();
  }

  const int rl = (l >> 4) * 4;
  #pragma unroll
  for (int j = 0; j < 8; ++j) {
    int n = n0 + j * 16 + lr;
    float bv = bias ? bias[n] : 0.f;
    #pragma unroll
    for (int i = 0; i < 2; ++i) {
      #pragma unroll
      for (int e = 0; e < 4; ++e) {
        int m = m0 + w * 32 + i * 16 + rl + e;
        if (m < M) {
          float v = acc[i][j][e] + bv;
          if constexpr (ADDC) v += Cin[zC + (size_t)m * N + n];
          v = activate<ACT>(v);
          if constexpr (XUP) {
            float lv = Cin[zC + (size_t)m * N + n];
            float xv = bf2f(Ah2[(size_t)m * N + n]) + bf2f(Al2[(size_t)m * N + n]);
            float o = v * lv + (1.f - v) * xv;
            u16 hh, ll; splitf(o, hh, ll);
            Oh[zC + (size_t)m * N + n] = hh;
            Ol[zC + (size_t)m * N + n] = ll;
          } else if constexpr (OSPL) {
            u16 hh, ll; splitf(v, hh, ll);
            Oh[zC + (size_t)m * N + n] = hh;
            Ol[zC + (size_t)m * N + n] = ll;
          } else {
            Co[zC + (size_t)m * N + n] = v;
          }
        }
      }
    }
  }
}

// ---------------- fused score + row-softmax (tile 128x256, full row) ----------------
// P[b][m][:] = softmax( xin[b,m,:] @ lstm[b]^T + mask[b,:] ), split-bf16 output.
__global__ __launch_bounds__(256) void score_sm(
    const u16* __restrict__ Ah, const u16* __restrict__ Al,
    const u16* __restrict__ Bh, const u16* __restrict__ Bl,
    const float* __restrict__ mask,
    u16* __restrict__ Oh, u16* __restrict__ Ol)
{
  __shared__ u16 AH[128][40];
  __shared__ u16 AL[128][40];
  __shared__ u16 BH[256][40];
  __shared__ u16 BL[256][40];

  const int tid = threadIdx.x;
  const int w = tid >> 6, l = tid & 63;
  const int m0 = blockIdx.x * 128;
  const int z  = blockIdx.y;
  const long zA = (long)z * (S_ * D_);
  const long zC = (long)z * (S_ * S_);

  f32x4 acc[2][16];
  #pragma unroll
  for (int i = 0; i < 2; ++i)
    #pragma unroll
    for (int j = 0; j < 16; ++j) acc[i][j] = (f32x4){0.f, 0.f, 0.f, 0.f};

  const int ar = tid >> 1, ahh = tid & 1;
  const int lr = l & 15, lk = (l >> 4) * 8;

  for (int kt = 0; kt < D_; kt += 32) {
    {
      const u16* ph = Ah + zA + (size_t)(m0 + ar) * D_ + kt + ahh * 16;
      const u16* pl = Al + zA + (size_t)(m0 + ar) * D_ + kt + ahh * 16;
      *(s16x8*)&AH[ar][ahh * 16] = *(const s16x8*)ph;
      *(s16x8*)&AH[ar][ahh * 16 + 8] = *(const s16x8*)(ph + 8);
      *(s16x8*)&AL[ar][ahh * 16] = *(const s16x8*)pl;
      *(s16x8*)&AL[ar][ahh * 16 + 8] = *(const s16x8*)(pl + 8);
    }
    #pragma unroll
    for (int h = 0; h < 2; ++h) {
      int r = h * 128 + ar;
      const u16* ph = Bh + zA + (size_t)r * D_ + kt + ahh * 16;
      const u16* pl = Bl + zA + (size_t)r * D_ + kt + ahh * 16;
      *(s16x8*)&BH[r][ahh * 16] = *(const s16x8*)ph;
      *(s16x8*)&BH[r][ahh * 16 + 8] = *(const s16x8*)(ph + 8);
      *(s16x8*)&BL[r][ahh * 16] = *(const s16x8*)pl;
      *(s16x8*)&BL[r][ahh * 16 + 8] = *(const s16x8*)(pl + 8);
    }
    __syncthreads();

    s16x8 afh[2], afl[2];
    #pragma unroll
    for (int i = 0; i < 2; ++i) {
      afh[i] = *(const s16x8*)&AH[w * 32 + i * 16 + lr][lk];
      afl[i] = *(const s16x8*)&AL[w * 32 + i * 16 + lr][lk];
    }
    #pragma unroll
    for (int j = 0; j < 16; ++j) {
      s16x8 bfh = *(const s16x8*)&BH[j * 16 + lr][lk];
      s16x8 bfl = *(const s16x8*)&BL[j * 16 + lr][lk];
      #pragma unroll
      for (int i = 0; i < 2; ++i) {
        acc[i][j] = __builtin_amdgcn_mfma_f32_16x16x32_bf16(afl[i], bfh, acc[i][j], 0, 0, 0);
        acc[i][j] = __builtin_amdgcn_mfma_f32_16x16x32_bf16(afh[i], bfl, acc[i][j], 0, 0, 0);
        acc[i][j] = __builtin_amdgcn_mfma_f32_16x16x32_bf16(afh[i], bfh, acc[i][j], 0, 0, 0);
      }
    }
    __syncthreads();
  }

  // epilogue: in-register row softmax. Lanes with equal (l>>4) share a row.
  const int rl = (l >> 4) * 4;
  float mk[16];
  #pragma unroll
  for (int j = 0; j < 16; ++j) mk[j] = mask[z * S_ + j * 16 + lr];

  #pragma unroll
  for (int i = 0; i < 2; ++i) {
    #pragma unroll
    for (int e = 0; e < 4; ++e) {
      float val[16];
      float vmax = -1e30f;
      #pragma unroll
      for (int j = 0; j < 16; ++j) {
        val[j] = acc[i][j][e] + mk[j];
        vmax = fmaxf(vmax, val[j]);
      }
      #pragma unroll
      for (int off = 1; off < 16; off <<= 1)
        vmax = fmaxf(vmax, __shfl_xor(vmax, off));
      float sum = 0.f;
      #pragma unroll
      for (int j = 0; j < 16; ++j) { val[j] = expf(val[j] - vmax); sum += val[j]; }
      #pragma unroll
      for (int off = 1; off < 16; off <<= 1)
        sum += __shfl_xor(sum, off);
      float inv = 1.f / sum;
      int r = m0 + w * 32 + i * 16 + rl + e;
      #pragma unroll
      for (int j = 0; j < 16; ++j) {
        u16 hh, ll; splitf(val[j] * inv, hh, ll);
        Oh[zC + (size_t)r * S_ + j * 16 + lr] = hh;
        Ol[zC + (size_t)r * S_ + j * 16 + lr] = ll;
      }
    }
  }
}

// ---------------- distributed LSTM (R9/R11-validated version) ----------------
// WF layout: q = (((dir*8+j)*4+w)*8+kt)*2+nt : hi at q*1024 + lane*8, lo at +512
__global__ __launch_bounds__(256) void wf_prep(
    const float* __restrict__ Wf, const float* __restrict__ Wb, u16* __restrict__ WF)
{
  int gid = blockIdx.x * 256 + threadIdx.x;   // 65536
  int lane = gid & 63;
  int nt = (gid >> 6) & 1;
  int kt = (gid >> 7) & 7;
  int w  = (gid >> 10) & 3;
  int j  = (gid >> 12) & 7;
  int dir = gid >> 15;
  const float* W = dir ? Wb : Wf;
  int r = w * 256 + j * 32 + nt * 16 + (lane & 15);
  int kb = kt * 32 + (lane >> 4) * 8;
  const float* src = W + (size_t)r * H_ + kb;
  u16 hh[8], ll[8];
  #pragma unroll
  for (int c = 0; c < 2; ++c) {
    float4 v = ((const float4*)src)[c];
    splitf(v.x, hh[c*4+0], ll[c*4+0]); splitf(v.y, hh[c*4+1], ll[c*4+1]);
    splitf(v.z, hh[c*4+2], ll[c*4+2]); splitf(v.w, hh[c*4+3], ll[c*4+3]);
  }
  size_t off = (size_t)(gid >> 6) * 1024 + (size_t)lane * 8;
  *(s16x8*)(WF + off)       = *(s16x8*)&hh[0];
  *(s16x8*)(WF + off + 512) = *(s16x8*)&ll[0];
}

// re-tag the entire ring to generation 3 (invalid for the first reads)
__global__ __launch_bounds__(256) void ring_init(u64* __restrict__ ring64)
{
  int i = blockIdx.x * 256 + threadIdx.x;   // 65536
  __hip_atomic_store(&ring64[i], (u64)3, __ATOMIC_RELAXED, __HIP_MEMORY_SCOPE_AGENT);
}

// grid 64: grp = bid&7 (dir*4+bg), j = bid>>3. 256 threads (4 waves).
// Self-validating tagged ring: u64 word = {fp32 h1 | fp32 h0 with 2-bit gen tag
// in mantissa LSBs}. gen = (t>>2)&3, slot = t&3. Poll data words directly.
__global__ __launch_bounds__(256, 1) void lstm_dist(
    const float* __restrict__ GX, const u16* __restrict__ WF,
    const int* __restrict__ lens, u16* __restrict__ outH, u16* __restrict__ outL,
    u64* __restrict__ ring64)
{
  const int bid = blockIdx.x;
  const int grp = bid & 7;
  const int j   = bid >> 3;
  const int dir = grp >> 2;
  const int bg  = grp & 3;
  const int b0g = bg * 16;
  const int tid = threadIdx.x;
  const int w = tid >> 6, l = tid & 63;

  const float* gx = GX + (size_t)dir * ((size_t)BS * G4);

  __shared__ int slen[16];
  __shared__ __align__(16) u16 AHs[16][264];
  __shared__ __align__(16) u16 ALs[16][264];
  __shared__ float act[2][4][16][33];    // double-buffered by t&1
  if (tid < 16) slen[tid] = lens[b0g + tid];
  __syncthreads();

  s16x8 wh[8][2], wl[8][2];
  #pragma unroll
  for (int kt = 0; kt < 8; ++kt)
    #pragma unroll
    for (int nt = 0; nt < 2; ++nt) {
      size_t q = ((size_t)(((dir * 8 + j) * 4 + w) * 8 + kt) * 2 + nt);
      const u16* p = WF + q * 1024 + (size_t)l * 8;
      wh[kt][nt] = *(const s16x8*)p;
      wl[kt][nt] = *(const s16x8*)(p + 512);
    }

  const int ub = tid >> 4;
  const int uu = (tid & 15) * 2;
  const int len_b = slen[ub];
  float c0s = 0.f, c1s = 0.f, h0s = 0.f, h1s = 0.f;

  const int lr = l & 15, lkb = (l >> 4) * 8;

  for (int t = 0; t < S_; ++t) {
    float gxv[2][4];
    #pragma unroll
    for (int nt = 0; nt < 2; ++nt)
      #pragma unroll
      for (int e = 0; e < 4; ++e) {
        int b = (l >> 4) * 4 + e;
        int len = slen[b];
        int pos = dir ? (t < len ? len - 1 - t : t) : t;
        gxv[nt][e] = gx[(size_t)((b0g + b) * S_ + pos) * G4 + (w * 256 + j * 32 + nt * 16 + lr)];
      }

    f32x4 acc[2];
    acc[0] = (f32x4){0.f, 0.f, 0.f, 0.f};
    acc[1] = (f32x4){0.f, 0.f, 0.f, 0.f};

    if (t > 0) {
      const unsigned gen = (unsigned)(((t - 1) >> 2) & 3);
      const int slot = (t - 1) & 3;
      u64* rb = ring64 + ((size_t)slot * 8 + grp) * (16 * 128);
      u64 v[8];
      unsigned need = 0xFFu;
      do {
        unsigned nn = 0;
        #pragma unroll
        for (int k = 0; k < 8; ++k)
          if ((need >> k) & 1)
            v[k] = __hip_atomic_load(&rb[k * 256 + tid], __ATOMIC_RELAXED, __HIP_MEMORY_SCOPE_AGENT);
        #pragma unroll
        for (int k = 0; k < 8; ++k)
          if (((need >> k) & 1) && ((unsigned)v[k] & 3u) != gen) nn |= 1u << k;
        need = nn;
      } while (need);
      #pragma unroll
      for (int k = 0; k < 8; ++k) {
        int idx = k * 256 + tid;
        int b = idx >> 7, p = idx & 127;
        float f0 = __uint_as_float((unsigned)v[k] & ~3u);
        float f1 = __uint_as_float((unsigned)(v[k] >> 32));
        u16 hh0, ll0, hh1, ll1;
        splitf(f0, hh0, ll0); splitf(f1, hh1, ll1);
        *(unsigned*)&AHs[b][2 * p] = (unsigned)hh0 | ((unsigned)hh1 << 16);
        *(unsigned*)&ALs[b][2 * p] = (unsigned)ll0 | ((unsigned)ll1 << 16);
      }
      __syncthreads();
      #pragma unroll
      for (int kt = 0; kt < 8; ++kt) {
        s16x8 ah = *(const s16x8*)&AHs[lr][kt * 32 + lkb];
        s16x8 al = *(const s16x8*)&ALs[lr][kt * 32 + lkb];
        #pragma unroll
        for (int nt = 0; nt < 2; ++nt) {
          acc[nt] = __builtin_amdgcn_mfma_f32_16x16x32_bf16(al, wh[kt][nt], acc[nt], 0, 0, 0);
          acc[nt] = __builtin_amdgcn_mfma_f32_16x16x32_bf16(ah, wl[kt][nt], acc[nt], 0, 0, 0);
          acc[nt] = __builtin_amdgcn_mfma_f32_16x16x32_bf16(ah, wh[kt][nt], acc[nt], 0, 0, 0);
        }
      }
    }

    const int pb = t & 1;
    #pragma unroll
    for (int nt = 0; nt < 2; ++nt)
      #pragma unroll
      for (int e = 0; e < 4; ++e) {
        float v = acc[nt][e] + gxv[nt][e];
        v = (w == 2) ? tanhf(v) : 1.f / (1.f + expf(-v));
        act[pb][w][(l >> 4) * 4 + e][nt * 16 + lr] = v;
      }
    __syncthreads();

    {
      int pos = dir ? (t < len_b ? len_b - 1 - t : t) : t;
      bool valid = t < len_b;
      float i0 = act[pb][0][ub][uu],     f0 = act[pb][1][ub][uu],     g0 = act[pb][2][ub][uu],     o0 = act[pb][3][ub][uu];
      float i1 = act[pb][0][ub][uu + 1], f1 = act[pb][1][ub][uu + 1], g1 = act[pb][2][ub][uu + 1], o1 = act[pb][3][ub][uu + 1];
      float cn0 = fmaf(f0, c0s, i0 * g0), cn1 = fmaf(f1, c1s, i1 * g1);
      float hn0 = o0 * tanhf(cn0), hn1 = o1 * tanhf(cn1);
      if (valid) { c0s = cn0; h0s = hn0; c1s = cn1; h1s = hn1; }
      unsigned gen = (unsigned)((t >> 2) & 3);
      unsigned a0 = (__float_as_uint(h0s) & ~3u) | gen;
      unsigned a1 = __float_as_uint(h1s);
      u64 word = ((u64)a1 << 32) | (u64)a0;
      const int slot = t & 3;
      size_t ridx = ((size_t)slot * 8 + grp) * (16 * 128) + (size_t)ub * 128 + j * 16 + (tid & 15);
      __hip_atomic_store(&ring64[ridx], word, __ATOMIC_RELAXED, __HIP_MEMORY_SCOPE_AGENT);
      float ov0 = valid ? hn0 : 0.f, ov1 = valid ? hn1 : 0.f;
      u16 oh0, qq0, oh1, qq1;
      splitf(ov0, oh0, qq0); splitf(ov1, oh1, qq1);
      size_t obase = (size_t)((b0g + ub) * S_ + pos) * (2 * H_) + dir * H_ + j * 32 + uu;
      *(ushort2*)&outH[obase] = make_ushort2(oh0, oh1);
      *(ushort2*)&outL[obase] = make_ushort2(qq0, qq1);
    }
    // no trailing barrier: act double-buffered; AHs writes gated by next
    // iteration's post-staging barrier.
  }
}

// span-based aspect mean: only the <=5 rows with amask==0 contribute
__global__ __launch_bounds__(512) void asps_k(
    const u16* __restrict__ lh, const u16* __restrict__ ll,
    const float* __restrict__ amask, const int* __restrict__ alen, float* __restrict__ asps)
{
  int b = blockIdx.x, tid = threadIdx.x;
  __shared__ int sstart;
  if (tid == 0) sstart = S_;
  __syncthreads();
  if (tid < S_ && amask[b * S_ + tid] == 0.f) atomicMin(&sstart, tid);
  __syncthreads();
  const int start = sstart;
  const int len = alen[b];
  float acc = 0.f;
  for (int k = 0; k < len; ++k) {
    size_t i = ((size_t)(b * S_ + start + k)) * D_ + tid;
    acc += bf2f(lh[i]) + bf2f(ll[i]);
  }
  asps[b * D_ + tid] = acc / (float)len;
}

__global__ __launch_bounds__(256) void final_sc_k(
    const float* __restrict__ Qp, const float* __restrict__ Kp,
    const float* __restrict__ smask, float* __restrict__ outsc)
{
  int b = blockIdx.x, tid = threadIdx.x;
  __shared__ float q[D_];
  q[tid] = Qp[b * D_ + tid];
  q[tid + 256] = Qp[b * D_ + tid + 256];
  __syncthreads();
  const float4* kr = (const float4*)(Kp + ((size_t)(b * S_ + tid)) * D_);
  float acc = 0.f;
  #pragma unroll 4
  for (int d = 0; d < D_ / 4; ++d) {
    float4 kv = kr[d];
    acc += q[4 * d] * kv.x + q[4 * d + 1] * kv.y + q[4 * d + 2] * kv.z + q[4 * d + 3] * kv.w;
  }
  float v = acc / sqrtf((float)D_) + smask[b * S_ + tid];
  float m = v;
  #pragma unroll
  for (int off = 32; off > 0; off >>= 1) m = fmaxf(m, __shfl_xor(m, off));
  __shared__ float r1[4];
  __shared__ float r2[4];
  const int w = tid >> 6, l = tid & 63;
  if (l == 0) r1[w] = m;
  __syncthreads();
  m = fmaxf(fmaxf(r1[0], r1[1]), fmaxf(r1[2], r1[3]));
  float e = expf(v - m);
  float s = e;
  #pragma unroll
  for (int off = 32; off > 0; off >>= 1) s += __shfl_xor(s, off);
  if (l == 0) r2[w] = s;
  __syncthreads();
  s = r2[0] + r2[1] + r2[2] + r2[3];
  outsc[b * S_ + tid] = e / s;
}

__global__ __launch_bounds__(512) void zero_outv(float* __restrict__ p)
{
  p[blockIdx.x * 512 + threadIdx.x] = 0.f;
}

// k-split weighted sum: grid (B, 8), each block sums a 32-k slice, atomicAdd.
__global__ __launch_bounds__(512) void out_vec_k(
    const float* __restrict__ sc, const float* __restrict__ Vp, float* __restrict__ outv)
{
  int b = blockIdx.x, d = threadIdx.x;
  int k0 = blockIdx.y * 32;
  __shared__ float s[32];
  if (d < 32) s[d] = sc[b * S_ + k0 + d];
  __syncthreads();
  float acc = 0.f;
  #pragma unroll
  for (int k = 0; k < 32; ++k)
    acc = fmaf(s[k], Vp[((size_t)(b * S_ + k0 + k)) * D_ + d], acc);
  atomicAdd(&outv[b * D_ + d], acc);
}

__global__ __launch_bounds__(192) void logits_k(
    const float* __restrict__ outv, const float* __restrict__ Wd,
    const float* __restrict__ bd, float* __restrict__ out)
{
  int b = blockIdx.x;
  int c = threadIdx.x >> 6, l = threadIdx.x & 63;
  float acc = 0.f;
  for (int d = l; d < D_; d += 64) acc = fmaf(outv[b * D_ + d], Wd[c * D_ + d], acc);
  #pragma unroll
  for (int off = 32; off > 0; off >>= 1) acc += __shfl_down(acc, off);
  if (l == 0) out[b * NC_ + c] = acc + bd[c];
}

extern "C" void kernel_launch(void* const* d_in, const int* in_sizes, int n_in,
                              void* d_out, int out_size, void* d_ws, size_t ws_size,
                              hipStream_t stream)
{
  const int*   seqs_id   = (const int*)d_in[0];
  const int*   seqs_len  = (const int*)d_in[1];
  const int*   asps_len  = (const int*)d_in[2];
  const float* asps_mask = (const float*)d_in[3];
  const float* sent_mask = (const float*)d_in[4];
  const float* embed     = (const float*)d_in[5];
  const float* Wih_f     = (const float*)d_in[6];
  const float* Whh_f     = (const float*)d_in[7];
  const float* b_f       = (const float*)d_in[8];
  const float* Wih_b     = (const float*)d_in[9];
  const float* Whh_b     = (const float*)d_in[10];
  const float* b_b       = (const float*)d_in[11];
  const float* W_cpt     = (const float*)d_in[12];
  const float* b_cpt     = (const float*)d_in[13];
  const float* W_as      = (const float*)d_in[14];
  const float* b_as      = (const float*)d_in[15];
  const float* Wq        = (const float*)d_in[16];
  const float* bq        = (const float*)d_in[17];
  const float* Wk        = (const float*)d_in[18];
  const float* bk        = (const float*)d_in[19];
  const float* Wv        = (const float*)d_in[20];
  const float* bv        = (const float*)d_in[21];
  const float* Wd        = (const float*)d_in[22];
  const float* bd        = (const float*)d_in[23];

  float* w = (float*)d_ws;
  size_t off = 0;
  auto alloc = [&](size_t words) { size_t o = off; off += words; return o; };
  struct Split { u16* h; u16* l; };
  auto salloc = [&](size_t n) {
    size_t o = alloc(n);
    Split s; s.h = (u16*)(w + o); s.l = (u16*)(w + o) + n; return s;
  };

  // ---- persistent ----
  const size_t off_wf   = alloc(524288);            // WF: 2 MB (1M u16)
  const size_t off_ring = alloc(131072);            // ring64: 64K u64 = 512 KB
  Split sWihF = salloc(4ul * H_ * D_);
  Split sWihB = salloc(4ul * H_ * D_);
  Split sWcpt = salloc((size_t)D_ * 2 * D_);
  Split sWas  = salloc((size_t)D_ * D_);
  Split sWk   = salloc((size_t)D_ * D_);
  Split sWv   = salloc((size_t)D_ * D_);
  Split sWq   = salloc((size_t)D_ * D_);
  Split sLstm = salloc((size_t)BS * D_);
  const size_t off_asps = alloc((size_t)B_ * D_);
  const size_t off_qp   = alloc((size_t)B_ * D_);
  const size_t off_outv = alloc((size_t)B_ * D_);

  // ---- dynamic region ----
  const size_t dyn0 = off;
  Split sXemb; sXemb.h = (u16*)(w + dyn0); sXemb.l = sXemb.h + (size_t)BS * D_;
  float* GX = w + dyn0 + (size_t)BS * D_;
  size_t p2 = dyn0;
  // sX2 overlays the old scoreF region (scoreF no longer needed)
  Split sX2;    sX2.h    = (u16*)(w + p2); sX2.l    = sX2.h + (size_t)BS * D_;         p2 += (size_t)B_ * S_ * S_;
  Split sScore; sScore.h = (u16*)(w + p2); sScore.l = sScore.h + (size_t)B_ * S_ * S_; p2 += (size_t)B_ * S_ * S_;
  Split sAttn;  sAttn.h  = (u16*)(w + p2); sAttn.l  = sAttn.h + (size_t)BS * D_;       p2 += (size_t)BS * D_;
  float* lin = w + p2;                    p2 += (size_t)BS * D_;
  float* scl = w + p2;                    p2 += (size_t)BS * D_;   // unused (kept for layout)
  Split sX;     sX.h     = (u16*)(w + p2); sX.l     = sX.h + (size_t)BS * D_;           p2 += (size_t)BS * D_;

  u16* WF      = (u16*)(w + off_wf);
  u64* ring64  = (u64*)(w + off_ring);
  float* aspsb = w + off_asps;
  float* qp    = w + off_qp;
  float* outv  = w + off_outv;
  float* Kp    = (float*)sAttn.h;
  float* Vp    = lin;
  float* logits = (float*)d_out;
  float* outsc  = (float*)d_out + B_ * NC_;
  (void)scl;

  // ---- prep ----
  ring_init<<<256, 256, 0, stream>>>(ring64);
  wf_prep<<<256, 256, 0, stream>>>(Whh_f, Whh_b, WF);
  split_w<<<512, 256, 0, stream>>>(Wih_f, sWihF.h, sWihF.l, H_ * D_);
  split_w<<<512, 256, 0, stream>>>(Wih_b, sWihB.h, sWihB.l, H_ * D_);
  split_w<<<512, 256, 0, stream>>>(W_cpt, sWcpt.h, sWcpt.l, D_ * 2 * D_ / 4);
  split_w<<<256, 256, 0, stream>>>(W_as, sWas.h, sWas.l, D_ * D_ / 4);
  split_w<<<256, 256, 0, stream>>>(Wk, sWk.h, sWk.l, D_ * D_ / 4);
  split_w<<<256, 256, 0, stream>>>(Wv, sWv.h, sWv.l, D_ * D_ / 4);
  split_w<<<256, 256, 0, stream>>>(Wq, sWq.h, sWq.l, D_ * D_ / 4);
  gather_split<<<BS * D_ / 4 / 256, 256, 0, stream>>>(embed, seqs_id, sXemb.h, sXemb.l);

  // ---- input GEMMs ----
  mgemm<0, true, false, true, true, false, false, false><<<dim3(128, 8, 1), 256, 0, stream>>>(
      nullptr, sXemb.h, sXemb.l, nullptr, nullptr, nullptr, sWihF.h, sWihF.l, b_f, nullptr,
      GX, nullptr, nullptr, BS, G4, D_, D_, 0, 0, 0, 0);
  mgemm<0, true, false, true, true, false, false, false><<<dim3(128, 8, 1), 256, 0, stream>>>(
      nullptr, sXemb.h, sXemb.l, nullptr, nullptr, nullptr, sWihB.h, sWihB.l, b_b, nullptr,
      GX + (size_t)BS * G4, nullptr, nullptr, BS, G4, D_, D_, 0, 0, 0, 0);

  lstm_dist<<<64, 256, 0, stream>>>(GX, WF, seqs_len, sLstm.h, sLstm.l, ring64);
  asps_k<<<B_, 512, 0, stream>>>(sLstm.h, sLstm.l, asps_mask, asps_len, aspsb);

  for (int it = 0; it < 2; ++it) {
    const Split xin  = (it == 0) ? sLstm : sX;
    const Split xout = (it == 0) ? sX    : sX2;
    // fused score + row softmax -> split P
    score_sm<<<dim3(2, B_), 256, 0, stream>>>(
        xin.h, xin.l, sLstm.h, sLstm.l, asps_mask, sScore.h, sScore.l);
    // attn = P @ lstm  (batched, KxN)
    mgemm<0, false, false, true, true, true, false, false><<<dim3(2, 4, B_), 256, 0, stream>>>(
        nullptr, sScore.h, sScore.l, nullptr, nullptr, nullptr, sLstm.h, sLstm.l, nullptr, nullptr,
        nullptr, sAttn.h, sAttn.l, S_, D_, S_, D_,
        (long)S_ * S_, (long)S_ * D_, (long)S_ * D_, 0);
    // lin = relu([attn | x] @ Wcpt^T + b)  -- fused dual-A, K=1024
    mgemm<1, true, false, true, true, false, true, false><<<dim3(128, 4, 1), 256, 0, stream>>>(
        nullptr, sAttn.h, sAttn.l, xin.h, xin.l, nullptr, sWcpt.h, sWcpt.l, b_cpt, nullptr,
        lin, nullptr, nullptr, BS, D_, 2 * D_, 2 * D_, 0, 0, 0, D_);
    // x' = sigmoid(x@Was^T+b)*lin + (1-s)*x   -- fused scale+xupdate, split out
    mgemm<2, true, false, true, true, false, false, true><<<dim3(128, 4, 1), 256, 0, stream>>>(
        nullptr, xin.h, xin.l, xin.h, xin.l, nullptr, sWas.h, sWas.l, b_as, lin,
        nullptr, xout.h, xout.l, BS, D_, D_, D_, 0, 0, 0, 0);
  }

  mgemm<0, true, false, true, true, false, false, false><<<dim3(128, 4, 1), 256, 0, stream>>>(
      nullptr, sX2.h, sX2.l, nullptr, nullptr, nullptr, sWk.h, sWk.l, bk, nullptr,
      Kp, nullptr, nullptr, BS, D_, D_, D_, 0, 0, 0, 0);
  mgemm<0, true, false, true, true, false, false, false><<<dim3(128, 4, 1), 256, 0, stream>>>(
      nullptr, sX2.h, sX2.l, nullptr, nullptr, nullptr, sWv.h, sWv.l, bv, nullptr,
      Vp, nullptr, nullptr, BS, D_, D_, D_, 0, 0, 0, 0);
  mgemm<0, true, false, false, true, false, false, false><<<dim3(1, 4, 1), 256, 0, stream>>>(
      aspsb, nullptr, nullptr, nullptr, nullptr, nullptr, sWq.h, sWq.l, bq, nullptr,
      qp, nullptr, nullptr, B_, D_, D_, D_, 0, 0, 0, 0);

  zero_outv<<<B_ * D_ / 512, 512, 0, stream>>>(outv);
  final_sc_k<<<B_, 256, 0, stream>>>(qp, Kp, sent_mask, outsc);
  out_vec_k<<<dim3(B_, 8, 1), 512, 0, stream>>>(outsc, Vp, outv);
  logits_k<<<B_, 192, 0, stream>>>(outv, Wd, bd, logits);
}